// Round 6
// baseline (252.065 us; speedup 1.0000x reference)
//
#include <hip/hip_runtime.h>

#define D_F 128
#define N_NODES 10000
#define N_EDGES 320000
#define TE 64
#define GRID 512
#define NTILES (N_EDGES / TE)

// ---- workspace layout: FULL path ----
#define WS_AGG       0u
#define WS_RC        5120000u                  // E uints  (row | col<<16)
#define WS_RADM      6400000u                  // E float2 (radial, mask)
#define WS_COUNTS    8960000u                  // 10240 ints
#define WS_CURSOR    9000960u                  // 10240 ints
#define WS_FULL_NEED 9041920u

// ---- workspace layout: FALLBACK (R4) path ----
#define F_WS_COUNTS 5120000u
#define F_WS_CURSOR 5160960u
#define F_WS_PERM   5201920u
#define F_WS_NEED   (5201920u + 1280000u)

typedef short s16x8 __attribute__((ext_vector_type(8)));
typedef float f32x4 __attribute__((ext_vector_type(4)));

union FragU { s16x8 v; unsigned u[4]; };

__device__ __forceinline__ unsigned cvt_pk_bf16(float lo, float hi) {
  unsigned r;
  asm("v_cvt_pk_bf16_f32 %0, %1, %2" : "=v"(r) : "v"(lo), "v"(hi));
  return r;
}
__device__ __forceinline__ float bf2f(unsigned short b) {
  union { unsigned u; float f; } v; v.u = ((unsigned)b) << 16; return v.f;
}
__device__ __forceinline__ float silu_f(float x) {
  float t = __builtin_amdgcn_exp2f(x * -1.44269504089f);
  return x * __builtin_amdgcn_rcpf(1.0f + t);
}
__device__ __forceinline__ void bar_lds() {
  asm volatile("s_waitcnt lgkmcnt(0)" ::: "memory");
  __builtin_amdgcn_sched_barrier(0);
  __builtin_amdgcn_s_barrier();
  __builtin_amdgcn_sched_barrier(0);
}
__device__ __forceinline__ void bar_all() {
  asm volatile("s_waitcnt vmcnt(0) lgkmcnt(0)" ::: "memory");
  __builtin_amdgcn_sched_barrier(0);
  __builtin_amdgcn_s_barrier();
  __builtin_amdgcn_sched_barrier(0);
}
__device__ __forceinline__ void gload_lds16(const unsigned short* g, char* l) {
  __builtin_amdgcn_global_load_lds(
      (const __attribute__((address_space(1))) unsigned int*)g,
      (__attribute__((address_space(3))) unsigned int*)l, 16, 0, 0);
}

// ================= prep: h -> bf16 (into d_out), zero agg + counts =================
__global__ __launch_bounds__(256)
void prep_kernel(const float* __restrict__ h, unsigned short* __restrict__ hbf,
                 float* __restrict__ agg, int* __restrict__ counts) {
  int g = blockIdx.x * 256 + threadIdx.x;
  int i = g * 4;
  if (i < N_NODES * D_F) {
    f32x4 v = *(const f32x4*)(h + i);
    *(unsigned*)(hbf + i)     = cvt_pk_bf16(v[0], v[1]);
    *(unsigned*)(hbf + i + 2) = cvt_pk_bf16(v[2], v[3]);
    *(f32x4*)(agg + i) = (f32x4){0.f, 0.f, 0.f, 0.f};
  }
  if (g < 10240) counts[g] = 0;
}

// ================= sort: histogram / scan / scatter =================
__global__ __launch_bounds__(256)
void hist_kernel(const int* __restrict__ ei, int* __restrict__ counts) {
  for (int e = blockIdx.x * 256 + threadIdx.x; e < N_EDGES; e += gridDim.x * 256)
    atomicAdd(&counts[ei[e]], 1);
}

__global__ __launch_bounds__(1024)
void scan_kernel(const int* __restrict__ counts, int* __restrict__ cursor) {
  __shared__ int sd[1024];
  const int t = threadIdx.x;
  const int base = t * 10;
  int loc[10]; int s = 0;
#pragma unroll
  for (int j = 0; j < 10; ++j) { loc[j] = counts[base + j]; s += loc[j]; }
  sd[t] = s;
  __syncthreads();
  for (int off = 1; off < 1024; off <<= 1) {
    int v = sd[t];
    int a = (t >= off) ? sd[t - off] : 0;
    __syncthreads();
    sd[t] = v + a;
    __syncthreads();
  }
  int run = sd[t] - s;
#pragma unroll
  for (int j = 0; j < 10; ++j) { cursor[base + j] = run; run += loc[j]; }
}

// full path: write sorted flat arrays directly (no perm)
__global__ __launch_bounds__(256)
void scatter2_kernel(const int* __restrict__ ei, const float* __restrict__ coord,
                     const float* __restrict__ edge_mask, int* __restrict__ cursor,
                     unsigned* __restrict__ rc, float2* __restrict__ radm) {
  for (int e = blockIdx.x * 256 + threadIdx.x; e < N_EDGES; e += gridDim.x * 256) {
    int r = ei[e], c = ei[N_EDGES + e];
    int pos = atomicAdd(&cursor[r], 1);
    float dx = coord[r * 3 + 0] - coord[c * 3 + 0];
    float dy = coord[r * 3 + 1] - coord[c * 3 + 1];
    float dz = coord[r * 3 + 2] - coord[c * 3 + 2];
    rc[pos] = (unsigned)r | ((unsigned)c << 16);
    radm[pos] = make_float2(dx * dx + dy * dy + dz * dz, edge_mask[e]);
  }
}

// fallback path scatter: perm only
__global__ __launch_bounds__(256)
void scatter_kernel(const int* __restrict__ ei, int* __restrict__ cursor,
                    int* __restrict__ perm) {
  for (int e = blockIdx.x * 256 + threadIdx.x; e < N_EDGES; e += gridDim.x * 256) {
    int r = ei[e];
    int p = atomicAdd(&cursor[r], 1);
    perm[p] = e;
  }
}

// ================= edge kernel (pipelined, DMA-staged, 2 blocks/CU) =================
// LDS map: A dbuf 2x32KB (k-major: [chunk 0..31][64 e][16B]) @0
//          M1 (16KB) and M2 (16KB) ALIAS the dead abuf_cur after GEMM1:
//            M1 = abuf_cur + 0, M2 = abuf_cur + 16384
//          meta dbuf 2x768B @65536
#define OFF_META 65536u
#define EDGE_LDS 67072u

__global__ __launch_bounds__(512, 4)
void egcl_edge_kernel(const unsigned short* __restrict__ hbf,
                      const float* __restrict__ We1, const float* __restrict__ be1,
                      const float* __restrict__ We2, const float* __restrict__ be2,
                      const unsigned* __restrict__ rc, const float2* __restrict__ radm,
                      float* __restrict__ agg) {
  extern __shared__ __attribute__((aligned(16))) char smem[];
  const int tid  = threadIdx.x;
  const int lane = tid & 63;
  const int wv   = tid >> 6;          // 0..7
  const int eg   = wv >> 2;           // 0..1 edge half
  const int cg   = wv & 3;            // 0..3 col quarter
  const int l15  = lane & 15;
  const int lg   = lane >> 4;
  const int c0   = cg * 32;
  const int col0 = c0 + l15;

  // ---- per-wave weight fragments in registers (bf16) ----
  FragU bw1[8][2];
  FragU bw2[4][2];
#pragma unroll
  for (int kt = 0; kt < 8; ++kt)
#pragma unroll
    for (int nt = 0; nt < 2; ++nt) {
      const int col = col0 + nt * 16;
      const int kb = kt * 32 + lg * 8;
#pragma unroll
      for (int j = 0; j < 4; ++j)
        bw1[kt][nt].u[j] = cvt_pk_bf16(We1[(kb + 2 * j) * D_F + col],
                                       We1[(kb + 2 * j + 1) * D_F + col]);
    }
#pragma unroll
  for (int kt = 0; kt < 4; ++kt)
#pragma unroll
    for (int nt = 0; nt < 2; ++nt) {
      const int col = col0 + nt * 16;
      const int kb = kt * 32 + lg * 8;
#pragma unroll
      for (int j = 0; j < 4; ++j)
        bw2[kt][nt].u[j] = cvt_pk_bf16(We2[(kb + 2 * j) * D_F + col],
                                       We2[(kb + 2 * j + 1) * D_F + col]);
    }
  const float bv1[2] = {be1[col0], be1[col0 + 16]};
  const float wlv[2] = {We1[256 * D_F + col0], We1[256 * D_F + col0 + 16]};
  const float bv2[2] = {be2[col0], be2[col0 + 16]};

  const int bid = (int)blockIdx.x;

  // ---- prologue: tile t0 ----
  int t = bid;
  unsigned crc; float2 crm;
  {
    crc = rc[t * TE + lane];
    crm = radm[t * TE + lane];
    if (tid < 64) {
      *(int*)(smem + OFF_META + 0 + tid * 4)     = (int)(crc & 0xFFFFu);
      *(float*)(smem + OFF_META + 256 + tid * 4) = crm.x;
      *(float*)(smem + OFF_META + 512 + tid * 4) = crm.y;
    }
    unsigned node = (wv < 4) ? (crc & 0xFFFFu) : (crc >> 16);
    const unsigned short* gsrc = hbf + (size_t)node * D_F;
    char* dst = smem;  // buf 0
#pragma unroll
    for (int k = 0; k < 4; ++k) {
      int c = wv * 4 + k;
      gload_lds16(gsrc + (c & 15) * 8, dst + c * 1024 + lane * 16);
    }
    int tn = t + GRID; int tnc = (tn < NTILES) ? tn : t;
    crc = rc[tnc * TE + lane];
    crm = radm[tnc * TE + lane];
  }
  bar_all();
  int p = 0;

  for (; t < NTILES; t += GRID) {
    char* abuf_cur = smem + p * 32768;
    char* abuf_nxt = smem + (p ^ 1) * 32768;
    char* m1base   = abuf_cur;            // aliases dead A after GEMM1
    char* m2base   = abuf_cur + 16384;
    const int mo = p * 768, mn = (p ^ 1) * 768;
    int*   rowsL = (int*)(smem + OFF_META + mo);
    float* radsL = (float*)(smem + OFF_META + mo + 256);
    float* msksL = (float*)(smem + OFF_META + mo + 512);

    // ---- P1: GEMM1 over A(t) ----
    f32x4 acc[2][2];
#pragma unroll
    for (int mt = 0; mt < 2; ++mt)
#pragma unroll
      for (int nt = 0; nt < 2; ++nt) acc[mt][nt] = (f32x4){0.f, 0.f, 0.f, 0.f};
    __builtin_amdgcn_s_setprio(1);
#pragma unroll
    for (int ks = 0; ks < 8; ++ks) {
      s16x8 a[2];
      const int chunk = ks * 4 + lg;
#pragma unroll
      for (int mt = 0; mt < 2; ++mt)
        a[mt] = *(const s16x8*)(abuf_cur + chunk * 1024 + (eg * 32 + mt * 16 + l15) * 16);
#pragma unroll
      for (int mt = 0; mt < 2; ++mt)
#pragma unroll
        for (int nt = 0; nt < 2; ++nt)
          acc[mt][nt] = __builtin_amdgcn_mfma_f32_16x16x32_bf16(a[mt], bw1[ks][nt].v,
                                                                acc[mt][nt], 0, 0, 0);
    }
    __builtin_amdgcn_s_setprio(0);
    // A(t) fully consumed by all waves before M1/M2 overwrite it:
    bar_lds();

    // ---- ep1: +be1 +radial*wlast, silu -> M1 (aliases A) ----
#pragma unroll
    for (int mt = 0; mt < 2; ++mt)
#pragma unroll
      for (int nt = 0; nt < 2; ++nt)
#pragma unroll
        for (int q = 0; q < 4; ++q) {
          int e = eg * 32 + mt * 16 + lg * 4 + q;
          float v = acc[mt][nt][q] + bv1[nt] + radsL[e] * wlv[nt];
          v = silu_f(v);
          *(unsigned short*)(m1base + (unsigned)(e * 256) +
                             ((unsigned)((c0 + nt * 16 + l15) * 2) ^
                              ((unsigned)((e & 7) << 4)))) =
              (unsigned short)cvt_pk_bf16(v, v);
        }
    bar_lds();

    // ---- P2: DMA A(t+1), write meta(t+1), prefetch meta(t+2) ----
    {
      unsigned node = (wv < 4) ? (crc & 0xFFFFu) : (crc >> 16);
      const unsigned short* gsrc = hbf + (size_t)node * D_F;
#pragma unroll
      for (int k = 0; k < 4; ++k) {
        int c = wv * 4 + k;
        gload_lds16(gsrc + (c & 15) * 8, abuf_nxt + c * 1024 + lane * 16);
      }
      if (tid < 64) {
        *(int*)(smem + OFF_META + mn + 0 + tid * 4)     = (int)(crc & 0xFFFFu);
        *(float*)(smem + OFF_META + mn + 256 + tid * 4) = crm.x;
        *(float*)(smem + OFF_META + mn + 512 + tid * 4) = crm.y;
      }
    }
    int t2 = t + 2 * GRID; int t2c = (t2 < NTILES) ? t2 : bid;
    unsigned nrc = rc[t2c * TE + lane];
    float2 nrm = radm[t2c * TE + lane];

    // ---- P4: GEMM2 over M1 ----
#pragma unroll
    for (int mt = 0; mt < 2; ++mt)
#pragma unroll
      for (int nt = 0; nt < 2; ++nt) acc[mt][nt] = (f32x4){0.f, 0.f, 0.f, 0.f};
    const unsigned rswz = (unsigned)((l15 & 7) << 4);
    __builtin_amdgcn_s_setprio(1);
#pragma unroll
    for (int ks = 0; ks < 4; ++ks) {
      s16x8 a[2];
      unsigned kb = ((unsigned)((ks * 32 + lg * 8) * 2)) ^ rswz;
#pragma unroll
      for (int mt = 0; mt < 2; ++mt)
        a[mt] = *(const s16x8*)(m1base +
                                (unsigned)((eg * 32 + mt * 16 + l15) * 256) + kb);
#pragma unroll
      for (int mt = 0; mt < 2; ++mt)
#pragma unroll
        for (int nt = 0; nt < 2; ++nt)
          acc[mt][nt] = __builtin_amdgcn_mfma_f32_16x16x32_bf16(a[mt], bw2[ks][nt].v,
                                                                acc[mt][nt], 0, 0, 0);
    }
    __builtin_amdgcn_s_setprio(0);
    // ---- ep2: silu*mask -> M2 ----
#pragma unroll
    for (int mt = 0; mt < 2; ++mt)
#pragma unroll
      for (int nt = 0; nt < 2; ++nt)
#pragma unroll
        for (int q = 0; q < 4; ++q) {
          int e = eg * 32 + mt * 16 + lg * 4 + q;
          float v = silu_f(acc[mt][nt][q] + bv2[nt]) * msksL[e];
          int col = c0 + nt * 16 + l15;
          *(unsigned short*)(m2base + (unsigned)(e * 256) +
                             ((unsigned)(col * 2) ^ ((unsigned)((e & 7) << 4)))) =
              (unsigned short)cvt_pk_bf16(v, v);
        }
    bar_lds();

    // ---- P6: segmented merge walk (16 edges per thread) ----
    {
      const int q4 = tid >> 7, colw = tid & 127;
      const int eb = q4 * 16;
      float a = 0.f;
      int cur = rowsL[eb];
#pragma unroll
      for (int i = 0; i < 16; ++i) {
        int e = eb + i;
        float v = bf2f(*(const unsigned short*)(
            m2base + (unsigned)(e * 256) +
            ((unsigned)(colw * 2) ^ ((unsigned)((e & 7) << 4)))));
        int r = rowsL[e];
        if (r != cur) {
          atomicAdd(agg + (size_t)cur * D_F + colw, a);
          a = 0.f; cur = r;
        }
        a += v;
      }
      atomicAdd(agg + (size_t)cur * D_F + colw, a);
    }
    // ---- P7: drain DMA, flip ----
    bar_all();
    crc = nrc; crm = nrm; p ^= 1;
  }
}

// ================= fallback edge kernel (R4, proven) =================
#define F_OFF_A    0u
#define F_OFF_M2   0u
#define F_OFF_M1   32768u
#define F_OFF_META 49152u
#define F_EDGE_LDS (49152u + 1024u)

template <bool SORTED>
__global__ __launch_bounds__(256)
void egcl_edge_fb(const float* __restrict__ h, const float* __restrict__ coord,
                  const float* __restrict__ edge_mask,
                  const float* __restrict__ We1, const float* __restrict__ be1,
                  const float* __restrict__ We2, const float* __restrict__ be2,
                  const int* __restrict__ ei, const int* __restrict__ perm,
                  float* __restrict__ agg) {
  extern __shared__ __attribute__((aligned(16))) char smem[];
  const int tid  = threadIdx.x;
  const int lane = tid & 63;
  const int wv   = tid >> 6;
  const int l15  = lane & 15;
  const int lg   = lane >> 4;
  const int c0   = wv * 32;
  const int col0 = c0 + l15;

  int*   rows = (int*)(smem + F_OFF_META);
  float* rads = (float*)(smem + F_OFF_META + 256);
  float* msks = (float*)(smem + F_OFF_META + 512);

  FragU bw1[8][2];
  FragU bw2[4][2];
#pragma unroll
  for (int kt = 0; kt < 8; ++kt)
#pragma unroll
    for (int nt = 0; nt < 2; ++nt) {
      const int col = col0 + nt * 16;
      const int kb = kt * 32 + lg * 8;
#pragma unroll
      for (int j = 0; j < 4; ++j)
        bw1[kt][nt].u[j] = cvt_pk_bf16(We1[(kb + 2 * j) * D_F + col],
                                       We1[(kb + 2 * j + 1) * D_F + col]);
    }
#pragma unroll
  for (int kt = 0; kt < 4; ++kt)
#pragma unroll
    for (int nt = 0; nt < 2; ++nt) {
      const int col = col0 + nt * 16;
      const int kb = kt * 32 + lg * 8;
#pragma unroll
      for (int j = 0; j < 4; ++j)
        bw2[kt][nt].u[j] = cvt_pk_bf16(We2[(kb + 2 * j) * D_F + col],
                                       We2[(kb + 2 * j + 1) * D_F + col]);
    }
  const float bv1[2] = {be1[col0], be1[col0 + 16]};
  const float wlv[2] = {We1[256 * D_F + col0], We1[256 * D_F + col0 + 16]};
  const float bv2[2] = {be2[col0], be2[col0 + 16]};

  const int se = tid >> 2;
  const int sq = tid & 3;
  const unsigned sswz = (unsigned)((se & 7) << 4);
  const unsigned rswz = (unsigned)((l15 & 7) << 4);

  for (int tile = (int)blockIdx.x; tile < NTILES; tile += (int)gridDim.x) {
    const int ebase = tile * TE;
    const int eidx = SORTED ? perm[ebase + se] : (ebase + se);
    const int n0 = ei[eidx];
    const int n1 = ei[N_EDGES + eidx];
    if (sq == 0) {
      float dx = coord[n0 * 3 + 0] - coord[n1 * 3 + 0];
      float dy = coord[n0 * 3 + 1] - coord[n1 * 3 + 1];
      float dz = coord[n0 * 3 + 2] - coord[n1 * 3 + 2];
      rows[se] = n0;
      rads[se] = dx * dx + dy * dy + dz * dz;
      msks[se] = edge_mask[eidx];
    }
#pragma unroll
    for (int pp = 0; pp < 2; ++pp) {
      const f32x4* src = (const f32x4*)(h + (pp ? n1 : n0) * D_F + sq * 32);
#pragma unroll
      for (int j = 0; j < 4; ++j) {
        f32x4 x0 = src[2 * j], x1 = src[2 * j + 1];
        FragU w;
        w.u[0] = cvt_pk_bf16(x0[0], x0[1]);
        w.u[1] = cvt_pk_bf16(x0[2], x0[3]);
        w.u[2] = cvt_pk_bf16(x1[0], x1[1]);
        w.u[3] = cvt_pk_bf16(x1[2], x1[3]);
        unsigned kb = (unsigned)(pp * 256 + sq * 64 + j * 16);
        *(s16x8*)(smem + F_OFF_A + (unsigned)(se * 512) + (kb ^ sswz)) = w.v;
      }
    }
    bar_lds();

    f32x4 acc[4][2];
#pragma unroll
    for (int mt = 0; mt < 4; ++mt)
#pragma unroll
      for (int nt = 0; nt < 2; ++nt) acc[mt][nt] = (f32x4){0.f, 0.f, 0.f, 0.f};
#pragma unroll
    for (int ks = 0; ks < 8; ++ks) {
      s16x8 a[4];
      unsigned kb = ((unsigned)((ks * 32 + lg * 8) * 2)) ^ rswz;
#pragma unroll
      for (int mt = 0; mt < 4; ++mt)
        a[mt] = *(const s16x8*)(smem + F_OFF_A + (unsigned)((mt * 16 + l15) * 512) + kb);
#pragma unroll
      for (int mt = 0; mt < 4; ++mt)
#pragma unroll
        for (int nt = 0; nt < 2; ++nt)
          acc[mt][nt] = __builtin_amdgcn_mfma_f32_16x16x32_bf16(a[mt], bw1[ks][nt].v,
                                                                acc[mt][nt], 0, 0, 0);
    }
#pragma unroll
    for (int mt = 0; mt < 4; ++mt)
#pragma unroll
      for (int nt = 0; nt < 2; ++nt)
#pragma unroll
        for (int q = 0; q < 4; ++q) {
          int e = mt * 16 + lg * 4 + q;
          float v = acc[mt][nt][q] + bv1[nt] + rads[e] * wlv[nt];
          v = silu_f(v);
          *(unsigned short*)(smem + F_OFF_M1 + (unsigned)(e * 256) +
                             ((unsigned)((c0 + nt * 16 + l15) * 2) ^
                              ((unsigned)((e & 7) << 4)))) =
              (unsigned short)cvt_pk_bf16(v, v);
        }
    bar_lds();

#pragma unroll
    for (int mt = 0; mt < 4; ++mt)
#pragma unroll
      for (int nt = 0; nt < 2; ++nt) acc[mt][nt] = (f32x4){0.f, 0.f, 0.f, 0.f};
#pragma unroll
    for (int ks = 0; ks < 4; ++ks) {
      s16x8 a[4];
      unsigned kb = ((unsigned)((ks * 32 + lg * 8) * 2)) ^ rswz;
#pragma unroll
      for (int mt = 0; mt < 4; ++mt)
        a[mt] = *(const s16x8*)(smem + F_OFF_M1 + (unsigned)((mt * 16 + l15) * 256) + kb);
#pragma unroll
      for (int mt = 0; mt < 4; ++mt)
#pragma unroll
        for (int nt = 0; nt < 2; ++nt)
          acc[mt][nt] = __builtin_amdgcn_mfma_f32_16x16x32_bf16(a[mt], bw2[ks][nt].v,
                                                                acc[mt][nt], 0, 0, 0);
    }
    if (SORTED) {
#pragma unroll
      for (int mt = 0; mt < 4; ++mt)
#pragma unroll
        for (int nt = 0; nt < 2; ++nt)
#pragma unroll
          for (int q = 0; q < 4; ++q) {
            int e = mt * 16 + lg * 4 + q;
            float v = silu_f(acc[mt][nt][q] + bv2[nt]) * msks[e];
            int col = c0 + nt * 16 + l15;
            *(unsigned short*)(smem + F_OFF_M2 + (unsigned)(e * 256) +
                               ((unsigned)(col * 2) ^ ((unsigned)((e & 7) << 4)))) =
                (unsigned short)cvt_pk_bf16(v, v);
          }
      bar_lds();
      {
        const int colw = tid & 127, half = tid >> 7;
        float a = 0.f;
        int cur = rows[half * 32];
#pragma unroll 8
        for (int i = 0; i < 32; ++i) {
          int e = half * 32 + i;
          float v = bf2f(*(const unsigned short*)(
              smem + F_OFF_M2 + (unsigned)(e * 256) +
              ((unsigned)(colw * 2) ^ ((unsigned)((e & 7) << 4)))));
          int r = rows[e];
          if (r != cur) { atomicAdd(agg + (size_t)cur * D_F + colw, a); a = 0.f; cur = r; }
          a += v;
        }
        atomicAdd(agg + (size_t)cur * D_F + colw, a);
      }
    } else {
#pragma unroll
      for (int mt = 0; mt < 4; ++mt)
#pragma unroll
        for (int q = 0; q < 4; ++q) {
          int e = mt * 16 + lg * 4 + q;
          int r = rows[e];
          float mk = msks[e];
#pragma unroll
          for (int nt = 0; nt < 2; ++nt) {
            float v = silu_f(acc[mt][nt][q] + bv2[nt]) * mk;
            atomicAdd(agg + (size_t)r * D_F + c0 + nt * 16 + l15, v);
          }
        }
    }
    bar_lds();
  }
}

// ================= node kernel (MFMA, residual) =================
#define NOFF_A  0u
#define NOFF_M1 32768u
#define NODE_LDS 49152u

__global__ __launch_bounds__(256)
void egcl_node_kernel(const float* __restrict__ h, const float* __restrict__ agg,
                      const float* __restrict__ Wn1, const float* __restrict__ bn1,
                      const float* __restrict__ Wn2, const float* __restrict__ bn2,
                      float* __restrict__ out) {
  extern __shared__ __attribute__((aligned(16))) char smem[];
  const int tid  = threadIdx.x;
  const int lane = tid & 63;
  const int wv   = tid >> 6;
  const int l15  = lane & 15;
  const int lg   = lane >> 4;
  const int c0   = wv * 32;
  const int col0 = c0 + l15;
  const int base = blockIdx.x * 64;

  FragU bw1[8][2];
  FragU bw2[4][2];
#pragma unroll
  for (int kt = 0; kt < 8; ++kt)
#pragma unroll
    for (int nt = 0; nt < 2; ++nt) {
      const int col = col0 + nt * 16;
      const int kb = kt * 32 + lg * 8;
#pragma unroll
      for (int j = 0; j < 4; ++j)
        bw1[kt][nt].u[j] = cvt_pk_bf16(Wn1[(kb + 2 * j) * D_F + col],
                                       Wn1[(kb + 2 * j + 1) * D_F + col]);
    }
#pragma unroll
  for (int kt = 0; kt < 4; ++kt)
#pragma unroll
    for (int nt = 0; nt < 2; ++nt) {
      const int col = col0 + nt * 16;
      const int kb = kt * 32 + lg * 8;
#pragma unroll
      for (int j = 0; j < 4; ++j)
        bw2[kt][nt].u[j] = cvt_pk_bf16(Wn2[(kb + 2 * j) * D_F + col],
                                       Wn2[(kb + 2 * j + 1) * D_F + col]);
    }
  const float bv1[2] = {bn1[col0], bn1[col0 + 16]};
  const float bv2[2] = {bn2[col0], bn2[col0 + 16]};

  const int se = tid >> 2;
  const int sq = tid & 3;
  const unsigned sswz = (unsigned)((se & 7) << 4);
  const unsigned rswz = (unsigned)((l15 & 7) << 4);
  const int node = base + se;

#pragma unroll
  for (int p = 0; p < 2; ++p) {
    FragU w;
    if (node < N_NODES) {
      const f32x4* src = (const f32x4*)((p ? agg : h) + node * D_F + sq * 32);
#pragma unroll
      for (int j = 0; j < 4; ++j) {
        f32x4 x0 = src[2 * j], x1 = src[2 * j + 1];
        w.u[0] = cvt_pk_bf16(x0[0], x0[1]);
        w.u[1] = cvt_pk_bf16(x0[2], x0[3]);
        w.u[2] = cvt_pk_bf16(x1[0], x1[1]);
        w.u[3] = cvt_pk_bf16(x1[2], x1[3]);
        unsigned kb = (unsigned)(p * 256 + sq * 64 + j * 16);
        *(s16x8*)(smem + NOFF_A + (unsigned)(se * 512) + (kb ^ sswz)) = w.v;
      }
    } else {
      w.u[0] = w.u[1] = w.u[2] = w.u[3] = 0u;
#pragma unroll
      for (int j = 0; j < 4; ++j) {
        unsigned kb = (unsigned)(p * 256 + sq * 64 + j * 16);
        *(s16x8*)(smem + NOFF_A + (unsigned)(se * 512) + (kb ^ sswz)) = w.v;
      }
    }
  }
  bar_lds();

  f32x4 acc[4][2];
#pragma unroll
  for (int mt = 0; mt < 4; ++mt)
#pragma unroll
    for (int nt = 0; nt < 2; ++nt) acc[mt][nt] = (f32x4){0.f, 0.f, 0.f, 0.f};
#pragma unroll
  for (int ks = 0; ks < 8; ++ks) {
    s16x8 a[4];
    unsigned kb = ((unsigned)((ks * 32 + lg * 8) * 2)) ^ rswz;
#pragma unroll
    for (int mt = 0; mt < 4; ++mt)
      a[mt] = *(const s16x8*)(smem + NOFF_A + (unsigned)((mt * 16 + l15) * 512) + kb);
#pragma unroll
    for (int mt = 0; mt < 4; ++mt)
#pragma unroll
      for (int nt = 0; nt < 2; ++nt)
        acc[mt][nt] = __builtin_amdgcn_mfma_f32_16x16x32_bf16(a[mt], bw1[ks][nt].v,
                                                              acc[mt][nt], 0, 0, 0);
  }
#pragma unroll
  for (int mt = 0; mt < 4; ++mt)
#pragma unroll
    for (int nt = 0; nt < 2; ++nt)
#pragma unroll
      for (int q = 0; q < 4; ++q) {
        int e = mt * 16 + lg * 4 + q;
        float v = silu_f(acc[mt][nt][q] + bv1[nt]);
        *(unsigned short*)(smem + NOFF_M1 + (unsigned)(e * 256) +
                           ((unsigned)((c0 + nt * 16 + l15) * 2) ^
                            ((unsigned)((e & 7) << 4)))) =
            (unsigned short)cvt_pk_bf16(v, v);
      }
  bar_lds();

#pragma unroll
  for (int mt = 0; mt < 4; ++mt)
#pragma unroll
    for (int nt = 0; nt < 2; ++nt) acc[mt][nt] = (f32x4){0.f, 0.f, 0.f, 0.f};
#pragma unroll
  for (int ks = 0; ks < 4; ++ks) {
    s16x8 a[4];
    unsigned kb = ((unsigned)((ks * 32 + lg * 8) * 2)) ^ rswz;
#pragma unroll
    for (int mt = 0; mt < 4; ++mt)
      a[mt] = *(const s16x8*)(smem + NOFF_M1 + (unsigned)((mt * 16 + l15) * 256) + kb);
#pragma unroll
    for (int mt = 0; mt < 4; ++mt)
#pragma unroll
      for (int nt = 0; nt < 2; ++nt)
        acc[mt][nt] = __builtin_amdgcn_mfma_f32_16x16x32_bf16(a[mt], bw2[ks][nt].v,
                                                              acc[mt][nt], 0, 0, 0);
  }
#pragma unroll
  for (int mt = 0; mt < 4; ++mt)
#pragma unroll
    for (int q = 0; q < 4; ++q) {
      int nd = base + mt * 16 + lg * 4 + q;
      if (nd < N_NODES) {
#pragma unroll
        for (int nt = 0; nt < 2; ++nt) {
          int col = c0 + nt * 16 + l15;
          out[nd * D_F + col] = h[nd * D_F + col] + acc[mt][nt][q] + bv2[nt];
        }
      }
    }
}

extern "C" void kernel_launch(void* const* d_in, const int* in_sizes, int n_in,
                              void* d_out, int out_size, void* d_ws, size_t ws_size,
                              hipStream_t stream) {
  (void)in_sizes; (void)n_in; (void)out_size;
  const float* h         = (const float*)d_in[0];
  const float* coord     = (const float*)d_in[1];
  const float* edge_mask = (const float*)d_in[2];
  const float* We1       = (const float*)d_in[3];
  const float* be1       = (const float*)d_in[4];
  const float* We2       = (const float*)d_in[5];
  const float* be2       = (const float*)d_in[6];
  const float* Wn1       = (const float*)d_in[7];
  const float* bn1       = (const float*)d_in[8];
  const float* Wn2       = (const float*)d_in[9];
  const float* bn2       = (const float*)d_in[10];
  const int*   ei        = (const int*)d_in[11];
  float* out = (float*)d_out;
  char* ws = (char*)d_ws;
  float* agg = (float*)(ws + WS_AGG);

  hipFuncSetAttribute((const void*)egcl_edge_kernel,
                      hipFuncAttributeMaxDynamicSharedMemorySize, (int)EDGE_LDS);
  hipFuncSetAttribute((const void*)egcl_node_kernel,
                      hipFuncAttributeMaxDynamicSharedMemorySize, (int)NODE_LDS);

  if (ws_size >= (size_t)WS_FULL_NEED) {
    unsigned* rcarr  = (unsigned*)(ws + WS_RC);
    float2*   radm   = (float2*)(ws + WS_RADM);
    int*      counts = (int*)(ws + WS_COUNTS);
    int*      cursor = (int*)(ws + WS_CURSOR);
    unsigned short* hbf = (unsigned short*)d_out;  // scratch; node kernel overwrites later

    prep_kernel<<<(N_NODES * D_F / 4 + 255) / 256, 256, 0, stream>>>(h, hbf, agg, counts);
    hist_kernel<<<512, 256, 0, stream>>>(ei, counts);
    scan_kernel<<<1, 1024, 0, stream>>>(counts, cursor);
    scatter2_kernel<<<512, 256, 0, stream>>>(ei, coord, edge_mask, cursor, rcarr, radm);
    egcl_edge_kernel<<<GRID, 512, EDGE_LDS, stream>>>(
        hbf, We1, be1, We2, be2, rcarr, radm, agg);
  } else if (ws_size >= (size_t)F_WS_NEED) {
    int* counts = (int*)(ws + F_WS_COUNTS);
    int* cursor = (int*)(ws + F_WS_CURSOR);
    int* perm   = (int*)(ws + F_WS_PERM);
    hipFuncSetAttribute((const void*)egcl_edge_fb<true>,
                        hipFuncAttributeMaxDynamicSharedMemorySize, (int)F_EDGE_LDS);
    hipMemsetAsync(ws, 0, F_WS_CURSOR, stream);
    hist_kernel<<<512, 256, 0, stream>>>(ei, counts);
    scan_kernel<<<1, 1024, 0, stream>>>(counts, cursor);
    scatter_kernel<<<512, 256, 0, stream>>>(ei, cursor, perm);
    egcl_edge_fb<true><<<768, 256, F_EDGE_LDS, stream>>>(
        h, coord, edge_mask, We1, be1, We2, be2, ei, perm, agg);
  } else {
    hipFuncSetAttribute((const void*)egcl_edge_fb<false>,
                        hipFuncAttributeMaxDynamicSharedMemorySize, (int)F_EDGE_LDS);
    hipMemsetAsync(agg, 0, (size_t)N_NODES * D_F * sizeof(float), stream);
    egcl_edge_fb<false><<<768, 256, F_EDGE_LDS, stream>>>(
        h, coord, edge_mask, We1, be1, We2, be2, ei, nullptr, agg);
  }
  egcl_node_kernel<<<(N_NODES + 63) / 64, 256, NODE_LDS, stream>>>(
      h, agg, Wn1, bn1, Wn2, bn2, out);
}

// Round 7
// 159.262 us; speedup vs baseline: 1.5827x; 1.5827x over previous
//
#include <hip/hip_runtime.h>

#define D_F 128
#define N_NODES 10000
#define N_EDGES 320000
#define TE 64
#define GRID 512
#define NTILES (N_EDGES / TE)

// ---- workspace layout: FULL path ----
#define WS_AGG       0u
#define WS_RC        5120000u                  // E uints  (row | col<<16)
#define WS_RADM      6400000u                  // E float2 (radial, mask)
#define WS_COUNTS    8960000u                  // 10240 ints
#define WS_CURSOR    9000960u                  // 10240 ints
#define WS_FULL_NEED 9041920u

// ---- workspace layout: FALLBACK (R4) path ----
#define F_WS_COUNTS 5120000u
#define F_WS_CURSOR 5160960u
#define F_WS_PERM   5201920u
#define F_WS_NEED   (5201920u + 1280000u)

typedef short s16x8 __attribute__((ext_vector_type(8)));
typedef float f32x4 __attribute__((ext_vector_type(4)));

union FragU { s16x8 v; unsigned u[4]; };

__device__ __forceinline__ unsigned cvt_pk_bf16(float lo, float hi) {
  unsigned r;
  asm("v_cvt_pk_bf16_f32 %0, %1, %2" : "=v"(r) : "v"(lo), "v"(hi));
  return r;
}
__device__ __forceinline__ float bf2f(unsigned short b) {
  union { unsigned u; float f; } v; v.u = ((unsigned)b) << 16; return v.f;
}
__device__ __forceinline__ float silu_f(float x) {
  float t = __builtin_amdgcn_exp2f(x * -1.44269504089f);
  return x * __builtin_amdgcn_rcpf(1.0f + t);
}
__device__ __forceinline__ void bar_lds() {
  asm volatile("s_waitcnt lgkmcnt(0)" ::: "memory");
  __builtin_amdgcn_sched_barrier(0);
  __builtin_amdgcn_s_barrier();
  __builtin_amdgcn_sched_barrier(0);
}
__device__ __forceinline__ void bar_all() {
  asm volatile("s_waitcnt vmcnt(0) lgkmcnt(0)" ::: "memory");
  __builtin_amdgcn_sched_barrier(0);
  __builtin_amdgcn_s_barrier();
  __builtin_amdgcn_sched_barrier(0);
}
__device__ __forceinline__ void gload_lds16(const unsigned short* g, char* l) {
  __builtin_amdgcn_global_load_lds(
      (const __attribute__((address_space(1))) unsigned int*)g,
      (__attribute__((address_space(3))) unsigned int*)l, 16, 0, 0);
}

// ================= prep: h -> bf16 (into d_out), zero agg + counts =================
__global__ __launch_bounds__(256)
void prep_kernel(const float* __restrict__ h, unsigned short* __restrict__ hbf,
                 float* __restrict__ agg, int* __restrict__ counts) {
  int g = blockIdx.x * 256 + threadIdx.x;
  int i = g * 4;
  if (i < N_NODES * D_F) {
    f32x4 v = *(const f32x4*)(h + i);
    *(unsigned*)(hbf + i)     = cvt_pk_bf16(v[0], v[1]);
    *(unsigned*)(hbf + i + 2) = cvt_pk_bf16(v[2], v[3]);
    *(f32x4*)(agg + i) = (f32x4){0.f, 0.f, 0.f, 0.f};
  }
  if (g < 10240) counts[g] = 0;
}

// ================= sort: histogram / scan / scatter =================
__global__ __launch_bounds__(256)
void hist_kernel(const int* __restrict__ ei, int* __restrict__ counts) {
  for (int e = blockIdx.x * 256 + threadIdx.x; e < N_EDGES; e += gridDim.x * 256)
    atomicAdd(&counts[ei[e]], 1);
}

__global__ __launch_bounds__(1024)
void scan_kernel(const int* __restrict__ counts, int* __restrict__ cursor) {
  __shared__ int sd[1024];
  const int t = threadIdx.x;
  const int base = t * 10;
  int loc[10]; int s = 0;
#pragma unroll
  for (int j = 0; j < 10; ++j) { loc[j] = counts[base + j]; s += loc[j]; }
  sd[t] = s;
  __syncthreads();
  for (int off = 1; off < 1024; off <<= 1) {
    int v = sd[t];
    int a = (t >= off) ? sd[t - off] : 0;
    __syncthreads();
    sd[t] = v + a;
    __syncthreads();
  }
  int run = sd[t] - s;
#pragma unroll
  for (int j = 0; j < 10; ++j) { cursor[base + j] = run; run += loc[j]; }
}

// full path: write sorted flat arrays directly (no perm)
__global__ __launch_bounds__(256)
void scatter2_kernel(const int* __restrict__ ei, const float* __restrict__ coord,
                     const float* __restrict__ edge_mask, int* __restrict__ cursor,
                     unsigned* __restrict__ rc, float2* __restrict__ radm) {
  for (int e = blockIdx.x * 256 + threadIdx.x; e < N_EDGES; e += gridDim.x * 256) {
    int r = ei[e], c = ei[N_EDGES + e];
    int pos = atomicAdd(&cursor[r], 1);
    float dx = coord[r * 3 + 0] - coord[c * 3 + 0];
    float dy = coord[r * 3 + 1] - coord[c * 3 + 1];
    float dz = coord[r * 3 + 2] - coord[c * 3 + 2];
    rc[pos] = (unsigned)r | ((unsigned)c << 16);
    radm[pos] = make_float2(dx * dx + dy * dy + dz * dz, edge_mask[e]);
  }
}

// fallback path scatter: perm only
__global__ __launch_bounds__(256)
void scatter_kernel(const int* __restrict__ ei, int* __restrict__ cursor,
                    int* __restrict__ perm) {
  for (int e = blockIdx.x * 256 + threadIdx.x; e < N_EDGES; e += gridDim.x * 256) {
    int r = ei[e];
    int p = atomicAdd(&cursor[r], 1);
    perm[p] = e;
  }
}

// ================= edge kernel (pipelined, DMA-staged, 2 blocks/CU) =================
// LDS map: A dbuf 2x32KB (k-major: [chunk 0..31][64 e][16B]) @0
//          M1 (16KB) and M2 (16KB) ALIAS the dead abuf_cur after GEMM1:
//            M1 = abuf_cur + 0, M2 = abuf_cur + 16384
//          meta dbuf 2x768B @65536
#define OFF_META 65536u
#define EDGE_LDS 67072u

// NOTE: 2nd launch_bounds arg measured (R6) to behave as min BLOCKS/CU on this
// toolchain for 512-thr blocks: (512,4) forced a 64-VGPR cap -> weight spill,
// FETCH 431 MB. (512,2) -> 128-VGPR cap, fits the 112-VGPR allocation.
__global__ __launch_bounds__(512, 2)
void egcl_edge_kernel(const unsigned short* __restrict__ hbf,
                      const float* __restrict__ We1, const float* __restrict__ be1,
                      const float* __restrict__ We2, const float* __restrict__ be2,
                      const unsigned* __restrict__ rc, const float2* __restrict__ radm,
                      float* __restrict__ agg) {
  extern __shared__ __attribute__((aligned(16))) char smem[];
  const int tid  = threadIdx.x;
  const int lane = tid & 63;
  const int wv   = tid >> 6;          // 0..7
  const int eg   = wv >> 2;           // 0..1 edge half
  const int cg   = wv & 3;            // 0..3 col quarter
  const int l15  = lane & 15;
  const int lg   = lane >> 4;
  const int c0   = cg * 32;
  const int col0 = c0 + l15;

  // ---- per-wave weight fragments in registers (bf16) ----
  FragU bw1[8][2];
  FragU bw2[4][2];
#pragma unroll
  for (int kt = 0; kt < 8; ++kt)
#pragma unroll
    for (int nt = 0; nt < 2; ++nt) {
      const int col = col0 + nt * 16;
      const int kb = kt * 32 + lg * 8;
#pragma unroll
      for (int j = 0; j < 4; ++j)
        bw1[kt][nt].u[j] = cvt_pk_bf16(We1[(kb + 2 * j) * D_F + col],
                                       We1[(kb + 2 * j + 1) * D_F + col]);
    }
#pragma unroll
  for (int kt = 0; kt < 4; ++kt)
#pragma unroll
    for (int nt = 0; nt < 2; ++nt) {
      const int col = col0 + nt * 16;
      const int kb = kt * 32 + lg * 8;
#pragma unroll
      for (int j = 0; j < 4; ++j)
        bw2[kt][nt].u[j] = cvt_pk_bf16(We2[(kb + 2 * j) * D_F + col],
                                       We2[(kb + 2 * j + 1) * D_F + col]);
    }
  const float bv1[2] = {be1[col0], be1[col0 + 16]};
  const float wlv[2] = {We1[256 * D_F + col0], We1[256 * D_F + col0 + 16]};
  const float bv2[2] = {be2[col0], be2[col0 + 16]};

  const int bid = (int)blockIdx.x;

  // ---- prologue: tile t0 ----
  int t = bid;
  unsigned crc; float2 crm;
  {
    crc = rc[t * TE + lane];
    crm = radm[t * TE + lane];
    if (tid < 64) {
      *(int*)(smem + OFF_META + 0 + tid * 4)     = (int)(crc & 0xFFFFu);
      *(float*)(smem + OFF_META + 256 + tid * 4) = crm.x;
      *(float*)(smem + OFF_META + 512 + tid * 4) = crm.y;
    }
    unsigned node = (wv < 4) ? (crc & 0xFFFFu) : (crc >> 16);
    const unsigned short* gsrc = hbf + (size_t)node * D_F;
    char* dst = smem;  // buf 0
#pragma unroll
    for (int k = 0; k < 4; ++k) {
      int c = wv * 4 + k;
      gload_lds16(gsrc + (c & 15) * 8, dst + c * 1024 + lane * 16);
    }
    int tn = t + GRID; int tnc = (tn < NTILES) ? tn : t;
    crc = rc[tnc * TE + lane];
    crm = radm[tnc * TE + lane];
  }
  bar_all();
  int p = 0;

  for (; t < NTILES; t += GRID) {
    char* abuf_cur = smem + p * 32768;
    char* abuf_nxt = smem + (p ^ 1) * 32768;
    char* m1base   = abuf_cur;            // aliases dead A after GEMM1
    char* m2base   = abuf_cur + 16384;
    const int mo = p * 768, mn = (p ^ 1) * 768;
    int*   rowsL = (int*)(smem + OFF_META + mo);
    float* radsL = (float*)(smem + OFF_META + mo + 256);
    float* msksL = (float*)(smem + OFF_META + mo + 512);

    // ---- P1: GEMM1 over A(t) ----
    f32x4 acc[2][2];
#pragma unroll
    for (int mt = 0; mt < 2; ++mt)
#pragma unroll
      for (int nt = 0; nt < 2; ++nt) acc[mt][nt] = (f32x4){0.f, 0.f, 0.f, 0.f};
    __builtin_amdgcn_s_setprio(1);
#pragma unroll
    for (int ks = 0; ks < 8; ++ks) {
      s16x8 a[2];
      const int chunk = ks * 4 + lg;
#pragma unroll
      for (int mt = 0; mt < 2; ++mt)
        a[mt] = *(const s16x8*)(abuf_cur + chunk * 1024 + (eg * 32 + mt * 16 + l15) * 16);
#pragma unroll
      for (int mt = 0; mt < 2; ++mt)
#pragma unroll
        for (int nt = 0; nt < 2; ++nt)
          acc[mt][nt] = __builtin_amdgcn_mfma_f32_16x16x32_bf16(a[mt], bw1[ks][nt].v,
                                                                acc[mt][nt], 0, 0, 0);
    }
    __builtin_amdgcn_s_setprio(0);
    // A(t) fully consumed by all waves before M1/M2 overwrite it:
    bar_lds();

    // ---- ep1: +be1 +radial*wlast, silu -> M1 (aliases A) ----
#pragma unroll
    for (int mt = 0; mt < 2; ++mt)
#pragma unroll
      for (int nt = 0; nt < 2; ++nt)
#pragma unroll
        for (int q = 0; q < 4; ++q) {
          int e = eg * 32 + mt * 16 + lg * 4 + q;
          float v = acc[mt][nt][q] + bv1[nt] + radsL[e] * wlv[nt];
          v = silu_f(v);
          *(unsigned short*)(m1base + (unsigned)(e * 256) +
                             ((unsigned)((c0 + nt * 16 + l15) * 2) ^
                              ((unsigned)((e & 7) << 4)))) =
              (unsigned short)cvt_pk_bf16(v, v);
        }
    bar_lds();

    // ---- P2: DMA A(t+1), write meta(t+1), prefetch meta(t+2) ----
    {
      unsigned node = (wv < 4) ? (crc & 0xFFFFu) : (crc >> 16);
      const unsigned short* gsrc = hbf + (size_t)node * D_F;
#pragma unroll
      for (int k = 0; k < 4; ++k) {
        int c = wv * 4 + k;
        gload_lds16(gsrc + (c & 15) * 8, abuf_nxt + c * 1024 + lane * 16);
      }
      if (tid < 64) {
        *(int*)(smem + OFF_META + mn + 0 + tid * 4)     = (int)(crc & 0xFFFFu);
        *(float*)(smem + OFF_META + mn + 256 + tid * 4) = crm.x;
        *(float*)(smem + OFF_META + mn + 512 + tid * 4) = crm.y;
      }
    }
    int t2 = t + 2 * GRID; int t2c = (t2 < NTILES) ? t2 : bid;
    unsigned nrc = rc[t2c * TE + lane];
    float2 nrm = radm[t2c * TE + lane];

    // ---- P4: GEMM2 over M1 ----
#pragma unroll
    for (int mt = 0; mt < 2; ++mt)
#pragma unroll
      for (int nt = 0; nt < 2; ++nt) acc[mt][nt] = (f32x4){0.f, 0.f, 0.f, 0.f};
    const unsigned rswz = (unsigned)((l15 & 7) << 4);
    __builtin_amdgcn_s_setprio(1);
#pragma unroll
    for (int ks = 0; ks < 4; ++ks) {
      s16x8 a[2];
      unsigned kb = ((unsigned)((ks * 32 + lg * 8) * 2)) ^ rswz;
#pragma unroll
      for (int mt = 0; mt < 2; ++mt)
        a[mt] = *(const s16x8*)(m1base +
                                (unsigned)((eg * 32 + mt * 16 + l15) * 256) + kb);
#pragma unroll
      for (int mt = 0; mt < 2; ++mt)
#pragma unroll
        for (int nt = 0; nt < 2; ++nt)
          acc[mt][nt] = __builtin_amdgcn_mfma_f32_16x16x32_bf16(a[mt], bw2[ks][nt].v,
                                                                acc[mt][nt], 0, 0, 0);
    }
    __builtin_amdgcn_s_setprio(0);
    // ---- ep2: silu*mask -> M2 ----
#pragma unroll
    for (int mt = 0; mt < 2; ++mt)
#pragma unroll
      for (int nt = 0; nt < 2; ++nt)
#pragma unroll
        for (int q = 0; q < 4; ++q) {
          int e = eg * 32 + mt * 16 + lg * 4 + q;
          float v = silu_f(acc[mt][nt][q] + bv2[nt]) * msksL[e];
          int col = c0 + nt * 16 + l15;
          *(unsigned short*)(m2base + (unsigned)(e * 256) +
                             ((unsigned)(col * 2) ^ ((unsigned)((e & 7) << 4)))) =
              (unsigned short)cvt_pk_bf16(v, v);
        }
    bar_lds();

    // ---- P6: segmented merge walk (16 edges per thread) ----
    {
      const int q4 = tid >> 7, colw = tid & 127;
      const int eb = q4 * 16;
      float a = 0.f;
      int cur = rowsL[eb];
#pragma unroll
      for (int i = 0; i < 16; ++i) {
        int e = eb + i;
        float v = bf2f(*(const unsigned short*)(
            m2base + (unsigned)(e * 256) +
            ((unsigned)(colw * 2) ^ ((unsigned)((e & 7) << 4)))));
        int r = rowsL[e];
        if (r != cur) {
          atomicAdd(agg + (size_t)cur * D_F + colw, a);
          a = 0.f; cur = r;
        }
        a += v;
      }
      atomicAdd(agg + (size_t)cur * D_F + colw, a);
    }
    // ---- P7: drain DMA, flip ----
    bar_all();
    crc = nrc; crm = nrm; p ^= 1;
  }
}

// ================= fallback edge kernel (R4, proven) =================
#define F_OFF_A    0u
#define F_OFF_M2   0u
#define F_OFF_M1   32768u
#define F_OFF_META 49152u
#define F_EDGE_LDS (49152u + 1024u)

template <bool SORTED>
__global__ __launch_bounds__(256)
void egcl_edge_fb(const float* __restrict__ h, const float* __restrict__ coord,
                  const float* __restrict__ edge_mask,
                  const float* __restrict__ We1, const float* __restrict__ be1,
                  const float* __restrict__ We2, const float* __restrict__ be2,
                  const int* __restrict__ ei, const int* __restrict__ perm,
                  float* __restrict__ agg) {
  extern __shared__ __attribute__((aligned(16))) char smem[];
  const int tid  = threadIdx.x;
  const int lane = tid & 63;
  const int wv   = tid >> 6;
  const int l15  = lane & 15;
  const int lg   = lane >> 4;
  const int c0   = wv * 32;
  const int col0 = c0 + l15;

  int*   rows = (int*)(smem + F_OFF_META);
  float* rads = (float*)(smem + F_OFF_META + 256);
  float* msks = (float*)(smem + F_OFF_META + 512);

  FragU bw1[8][2];
  FragU bw2[4][2];
#pragma unroll
  for (int kt = 0; kt < 8; ++kt)
#pragma unroll
    for (int nt = 0; nt < 2; ++nt) {
      const int col = col0 + nt * 16;
      const int kb = kt * 32 + lg * 8;
#pragma unroll
      for (int j = 0; j < 4; ++j)
        bw1[kt][nt].u[j] = cvt_pk_bf16(We1[(kb + 2 * j) * D_F + col],
                                       We1[(kb + 2 * j + 1) * D_F + col]);
    }
#pragma unroll
  for (int kt = 0; kt < 4; ++kt)
#pragma unroll
    for (int nt = 0; nt < 2; ++nt) {
      const int col = col0 + nt * 16;
      const int kb = kt * 32 + lg * 8;
#pragma unroll
      for (int j = 0; j < 4; ++j)
        bw2[kt][nt].u[j] = cvt_pk_bf16(We2[(kb + 2 * j) * D_F + col],
                                       We2[(kb + 2 * j + 1) * D_F + col]);
    }
  const float bv1[2] = {be1[col0], be1[col0 + 16]};
  const float wlv[2] = {We1[256 * D_F + col0], We1[256 * D_F + col0 + 16]};
  const float bv2[2] = {be2[col0], be2[col0 + 16]};

  const int se = tid >> 2;
  const int sq = tid & 3;
  const unsigned sswz = (unsigned)((se & 7) << 4);
  const unsigned rswz = (unsigned)((l15 & 7) << 4);

  for (int tile = (int)blockIdx.x; tile < NTILES; tile += (int)gridDim.x) {
    const int ebase = tile * TE;
    const int eidx = SORTED ? perm[ebase + se] : (ebase + se);
    const int n0 = ei[eidx];
    const int n1 = ei[N_EDGES + eidx];
    if (sq == 0) {
      float dx = coord[n0 * 3 + 0] - coord[n1 * 3 + 0];
      float dy = coord[n0 * 3 + 1] - coord[n1 * 3 + 1];
      float dz = coord[n0 * 3 + 2] - coord[n1 * 3 + 2];
      rows[se] = n0;
      rads[se] = dx * dx + dy * dy + dz * dz;
      msks[se] = edge_mask[eidx];
    }
#pragma unroll
    for (int pp = 0; pp < 2; ++pp) {
      const f32x4* src = (const f32x4*)(h + (pp ? n1 : n0) * D_F + sq * 32);
#pragma unroll
      for (int j = 0; j < 4; ++j) {
        f32x4 x0 = src[2 * j], x1 = src[2 * j + 1];
        FragU w;
        w.u[0] = cvt_pk_bf16(x0[0], x0[1]);
        w.u[1] = cvt_pk_bf16(x0[2], x0[3]);
        w.u[2] = cvt_pk_bf16(x1[0], x1[1]);
        w.u[3] = cvt_pk_bf16(x1[2], x1[3]);
        unsigned kb = (unsigned)(pp * 256 + sq * 64 + j * 16);
        *(s16x8*)(smem + F_OFF_A + (unsigned)(se * 512) + (kb ^ sswz)) = w.v;
      }
    }
    bar_lds();

    f32x4 acc[4][2];
#pragma unroll
    for (int mt = 0; mt < 4; ++mt)
#pragma unroll
      for (int nt = 0; nt < 2; ++nt) acc[mt][nt] = (f32x4){0.f, 0.f, 0.f, 0.f};
#pragma unroll
    for (int ks = 0; ks < 8; ++ks) {
      s16x8 a[4];
      unsigned kb = ((unsigned)((ks * 32 + lg * 8) * 2)) ^ rswz;
#pragma unroll
      for (int mt = 0; mt < 4; ++mt)
        a[mt] = *(const s16x8*)(smem + F_OFF_A + (unsigned)((mt * 16 + l15) * 512) + kb);
#pragma unroll
      for (int mt = 0; mt < 4; ++mt)
#pragma unroll
        for (int nt = 0; nt < 2; ++nt)
          acc[mt][nt] = __builtin_amdgcn_mfma_f32_16x16x32_bf16(a[mt], bw1[ks][nt].v,
                                                                acc[mt][nt], 0, 0, 0);
    }
#pragma unroll
    for (int mt = 0; mt < 4; ++mt)
#pragma unroll
      for (int nt = 0; nt < 2; ++nt)
#pragma unroll
        for (int q = 0; q < 4; ++q) {
          int e = mt * 16 + lg * 4 + q;
          float v = acc[mt][nt][q] + bv1[nt] + rads[e] * wlv[nt];
          v = silu_f(v);
          *(unsigned short*)(smem + F_OFF_M1 + (unsigned)(e * 256) +
                             ((unsigned)((c0 + nt * 16 + l15) * 2) ^
                              ((unsigned)((e & 7) << 4)))) =
              (unsigned short)cvt_pk_bf16(v, v);
        }
    bar_lds();

#pragma unroll
    for (int mt = 0; mt < 4; ++mt)
#pragma unroll
      for (int nt = 0; nt < 2; ++nt) acc[mt][nt] = (f32x4){0.f, 0.f, 0.f, 0.f};
#pragma unroll
    for (int ks = 0; ks < 4; ++ks) {
      s16x8 a[4];
      unsigned kb = ((unsigned)((ks * 32 + lg * 8) * 2)) ^ rswz;
#pragma unroll
      for (int mt = 0; mt < 4; ++mt)
        a[mt] = *(const s16x8*)(smem + F_OFF_M1 + (unsigned)((mt * 16 + l15) * 256) + kb);
#pragma unroll
      for (int mt = 0; mt < 4; ++mt)
#pragma unroll
        for (int nt = 0; nt < 2; ++nt)
          acc[mt][nt] = __builtin_amdgcn_mfma_f32_16x16x32_bf16(a[mt], bw2[ks][nt].v,
                                                                acc[mt][nt], 0, 0, 0);
    }
    if (SORTED) {
#pragma unroll
      for (int mt = 0; mt < 4; ++mt)
#pragma unroll
        for (int nt = 0; nt < 2; ++nt)
#pragma unroll
          for (int q = 0; q < 4; ++q) {
            int e = mt * 16 + lg * 4 + q;
            float v = silu_f(acc[mt][nt][q] + bv2[nt]) * msks[e];
            int col = c0 + nt * 16 + l15;
            *(unsigned short*)(smem + F_OFF_M2 + (unsigned)(e * 256) +
                               ((unsigned)(col * 2) ^ ((unsigned)((e & 7) << 4)))) =
                (unsigned short)cvt_pk_bf16(v, v);
          }
      bar_lds();
      {
        const int colw = tid & 127, half = tid >> 7;
        float a = 0.f;
        int cur = rows[half * 32];
#pragma unroll 8
        for (int i = 0; i < 32; ++i) {
          int e = half * 32 + i;
          float v = bf2f(*(const unsigned short*)(
              smem + F_OFF_M2 + (unsigned)(e * 256) +
              ((unsigned)(colw * 2) ^ ((unsigned)((e & 7) << 4)))));
          int r = rows[e];
          if (r != cur) { atomicAdd(agg + (size_t)cur * D_F + colw, a); a = 0.f; cur = r; }
          a += v;
        }
        atomicAdd(agg + (size_t)cur * D_F + colw, a);
      }
    } else {
#pragma unroll
      for (int mt = 0; mt < 4; ++mt)
#pragma unroll
        for (int q = 0; q < 4; ++q) {
          int e = mt * 16 + lg * 4 + q;
          int r = rows[e];
          float mk = msks[e];
#pragma unroll
          for (int nt = 0; nt < 2; ++nt) {
            float v = silu_f(acc[mt][nt][q] + bv2[nt]) * mk;
            atomicAdd(agg + (size_t)r * D_F + c0 + nt * 16 + l15, v);
          }
        }
    }
    bar_lds();
  }
}

// ================= node kernel (MFMA, residual) =================
#define NOFF_A  0u
#define NOFF_M1 32768u
#define NODE_LDS 49152u

__global__ __launch_bounds__(256)
void egcl_node_kernel(const float* __restrict__ h, const float* __restrict__ agg,
                      const float* __restrict__ Wn1, const float* __restrict__ bn1,
                      const float* __restrict__ Wn2, const float* __restrict__ bn2,
                      float* __restrict__ out) {
  extern __shared__ __attribute__((aligned(16))) char smem[];
  const int tid  = threadIdx.x;
  const int lane = tid & 63;
  const int wv   = tid >> 6;
  const int l15  = lane & 15;
  const int lg   = lane >> 4;
  const int c0   = wv * 32;
  const int col0 = c0 + l15;
  const int base = blockIdx.x * 64;

  FragU bw1[8][2];
  FragU bw2[4][2];
#pragma unroll
  for (int kt = 0; kt < 8; ++kt)
#pragma unroll
    for (int nt = 0; nt < 2; ++nt) {
      const int col = col0 + nt * 16;
      const int kb = kt * 32 + lg * 8;
#pragma unroll
      for (int j = 0; j < 4; ++j)
        bw1[kt][nt].u[j] = cvt_pk_bf16(Wn1[(kb + 2 * j) * D_F + col],
                                       Wn1[(kb + 2 * j + 1) * D_F + col]);
    }
#pragma unroll
  for (int kt = 0; kt < 4; ++kt)
#pragma unroll
    for (int nt = 0; nt < 2; ++nt) {
      const int col = col0 + nt * 16;
      const int kb = kt * 32 + lg * 8;
#pragma unroll
      for (int j = 0; j < 4; ++j)
        bw2[kt][nt].u[j] = cvt_pk_bf16(Wn2[(kb + 2 * j) * D_F + col],
                                       Wn2[(kb + 2 * j + 1) * D_F + col]);
    }
  const float bv1[2] = {bn1[col0], bn1[col0 + 16]};
  const float bv2[2] = {bn2[col0], bn2[col0 + 16]};

  const int se = tid >> 2;
  const int sq = tid & 3;
  const unsigned sswz = (unsigned)((se & 7) << 4);
  const unsigned rswz = (unsigned)((l15 & 7) << 4);
  const int node = base + se;

#pragma unroll
  for (int p = 0; p < 2; ++p) {
    FragU w;
    if (node < N_NODES) {
      const f32x4* src = (const f32x4*)((p ? agg : h) + node * D_F + sq * 32);
#pragma unroll
      for (int j = 0; j < 4; ++j) {
        f32x4 x0 = src[2 * j], x1 = src[2 * j + 1];
        w.u[0] = cvt_pk_bf16(x0[0], x0[1]);
        w.u[1] = cvt_pk_bf16(x0[2], x0[3]);
        w.u[2] = cvt_pk_bf16(x1[0], x1[1]);
        w.u[3] = cvt_pk_bf16(x1[2], x1[3]);
        unsigned kb = (unsigned)(p * 256 + sq * 64 + j * 16);
        *(s16x8*)(smem + NOFF_A + (unsigned)(se * 512) + (kb ^ sswz)) = w.v;
      }
    } else {
      w.u[0] = w.u[1] = w.u[2] = w.u[3] = 0u;
#pragma unroll
      for (int j = 0; j < 4; ++j) {
        unsigned kb = (unsigned)(p * 256 + sq * 64 + j * 16);
        *(s16x8*)(smem + NOFF_A + (unsigned)(se * 512) + (kb ^ sswz)) = w.v;
      }
    }
  }
  bar_lds();

  f32x4 acc[4][2];
#pragma unroll
  for (int mt = 0; mt < 4; ++mt)
#pragma unroll
    for (int nt = 0; nt < 2; ++nt) acc[mt][nt] = (f32x4){0.f, 0.f, 0.f, 0.f};
#pragma unroll
  for (int ks = 0; ks < 8; ++ks) {
    s16x8 a[4];
    unsigned kb = ((unsigned)((ks * 32 + lg * 8) * 2)) ^ rswz;
#pragma unroll
    for (int mt = 0; mt < 4; ++mt)
      a[mt] = *(const s16x8*)(smem + NOFF_A + (unsigned)((mt * 16 + l15) * 512) + kb);
#pragma unroll
    for (int mt = 0; mt < 4; ++mt)
#pragma unroll
      for (int nt = 0; nt < 2; ++nt)
        acc[mt][nt] = __builtin_amdgcn_mfma_f32_16x16x32_bf16(a[mt], bw1[ks][nt].v,
                                                              acc[mt][nt], 0, 0, 0);
  }
#pragma unroll
  for (int mt = 0; mt < 4; ++mt)
#pragma unroll
    for (int nt = 0; nt < 2; ++nt)
#pragma unroll
      for (int q = 0; q < 4; ++q) {
        int e = mt * 16 + lg * 4 + q;
        float v = silu_f(acc[mt][nt][q] + bv1[nt]);
        *(unsigned short*)(smem + NOFF_M1 + (unsigned)(e * 256) +
                           ((unsigned)((c0 + nt * 16 + l15) * 2) ^
                            ((unsigned)((e & 7) << 4)))) =
            (unsigned short)cvt_pk_bf16(v, v);
      }
  bar_lds();

#pragma unroll
  for (int mt = 0; mt < 4; ++mt)
#pragma unroll
    for (int nt = 0; nt < 2; ++nt) acc[mt][nt] = (f32x4){0.f, 0.f, 0.f, 0.f};
#pragma unroll
  for (int ks = 0; ks < 4; ++ks) {
    s16x8 a[4];
    unsigned kb = ((unsigned)((ks * 32 + lg * 8) * 2)) ^ rswz;
#pragma unroll
    for (int mt = 0; mt < 4; ++mt)
      a[mt] = *(const s16x8*)(smem + NOFF_M1 + (unsigned)((mt * 16 + l15) * 256) + kb);
#pragma unroll
    for (int mt = 0; mt < 4; ++mt)
#pragma unroll
      for (int nt = 0; nt < 2; ++nt)
        acc[mt][nt] = __builtin_amdgcn_mfma_f32_16x16x32_bf16(a[mt], bw2[ks][nt].v,
                                                              acc[mt][nt], 0, 0, 0);
  }
#pragma unroll
  for (int mt = 0; mt < 4; ++mt)
#pragma unroll
    for (int q = 0; q < 4; ++q) {
      int nd = base + mt * 16 + lg * 4 + q;
      if (nd < N_NODES) {
#pragma unroll
        for (int nt = 0; nt < 2; ++nt) {
          int col = c0 + nt * 16 + l15;
          out[nd * D_F + col] = h[nd * D_F + col] + acc[mt][nt][q] + bv2[nt];
        }
      }
    }
}

extern "C" void kernel_launch(void* const* d_in, const int* in_sizes, int n_in,
                              void* d_out, int out_size, void* d_ws, size_t ws_size,
                              hipStream_t stream) {
  (void)in_sizes; (void)n_in; (void)out_size;
  const float* h         = (const float*)d_in[0];
  const float* coord     = (const float*)d_in[1];
  const float* edge_mask = (const float*)d_in[2];
  const float* We1       = (const float*)d_in[3];
  const float* be1       = (const float*)d_in[4];
  const float* We2       = (const float*)d_in[5];
  const float* be2       = (const float*)d_in[6];
  const float* Wn1       = (const float*)d_in[7];
  const float* bn1       = (const float*)d_in[8];
  const float* Wn2       = (const float*)d_in[9];
  const float* bn2       = (const float*)d_in[10];
  const int*   ei        = (const int*)d_in[11];
  float* out = (float*)d_out;
  char* ws = (char*)d_ws;
  float* agg = (float*)(ws + WS_AGG);

  hipFuncSetAttribute((const void*)egcl_edge_kernel,
                      hipFuncAttributeMaxDynamicSharedMemorySize, (int)EDGE_LDS);
  hipFuncSetAttribute((const void*)egcl_node_kernel,
                      hipFuncAttributeMaxDynamicSharedMemorySize, (int)NODE_LDS);

  if (ws_size >= (size_t)WS_FULL_NEED) {
    unsigned* rcarr  = (unsigned*)(ws + WS_RC);
    float2*   radm   = (float2*)(ws + WS_RADM);
    int*      counts = (int*)(ws + WS_COUNTS);
    int*      cursor = (int*)(ws + WS_CURSOR);
    unsigned short* hbf = (unsigned short*)d_out;  // scratch; node kernel overwrites later

    prep_kernel<<<(N_NODES * D_F / 4 + 255) / 256, 256, 0, stream>>>(h, hbf, agg, counts);
    hist_kernel<<<512, 256, 0, stream>>>(ei, counts);
    scan_kernel<<<1, 1024, 0, stream>>>(counts, cursor);
    scatter2_kernel<<<512, 256, 0, stream>>>(ei, coord, edge_mask, cursor, rcarr, radm);
    egcl_edge_kernel<<<GRID, 512, EDGE_LDS, stream>>>(
        hbf, We1, be1, We2, be2, rcarr, radm, agg);
  } else if (ws_size >= (size_t)F_WS_NEED) {
    int* counts = (int*)(ws + F_WS_COUNTS);
    int* cursor = (int*)(ws + F_WS_CURSOR);
    int* perm   = (int*)(ws + F_WS_PERM);
    hipFuncSetAttribute((const void*)egcl_edge_fb<true>,
                        hipFuncAttributeMaxDynamicSharedMemorySize, (int)F_EDGE_LDS);
    hipMemsetAsync(ws, 0, F_WS_CURSOR, stream);
    hist_kernel<<<512, 256, 0, stream>>>(ei, counts);
    scan_kernel<<<1, 1024, 0, stream>>>(counts, cursor);
    scatter_kernel<<<512, 256, 0, stream>>>(ei, cursor, perm);
    egcl_edge_fb<true><<<768, 256, F_EDGE_LDS, stream>>>(
        h, coord, edge_mask, We1, be1, We2, be2, ei, perm, agg);
  } else {
    hipFuncSetAttribute((const void*)egcl_edge_fb<false>,
                        hipFuncAttributeMaxDynamicSharedMemorySize, (int)F_EDGE_LDS);
    hipMemsetAsync(agg, 0, (size_t)N_NODES * D_F * sizeof(float), stream);
    egcl_edge_fb<false><<<768, 256, F_EDGE_LDS, stream>>>(
        h, coord, edge_mask, We1, be1, We2, be2, ei, nullptr, agg);
  }
  egcl_node_kernel<<<(N_NODES + 63) / 64, 256, NODE_LDS, stream>>>(
      h, agg, Wn1, bn1, Wn2, bn2, out);
}

// Round 8
// 156.780 us; speedup vs baseline: 1.6078x; 1.0158x over previous
//
#include <hip/hip_runtime.h>

#define D_F 128
#define N_NODES 10000
#define N_EDGES 320000
#define TE 64
#define GRID 512
#define NTILES (N_EDGES / TE)

// ---- workspace layout: FULL path ----
#define WS_AGG       0u
#define WS_RC        5120000u                  // E uints  (row | col<<16)
#define WS_RADM      6400000u                  // E float2 (radial, mask)
#define WS_COUNTS    8960000u                  // 10240 ints
#define WS_CURSOR    9000960u                  // 10240 ints
#define WS_FULL_NEED 9041920u

// ---- workspace layout: FALLBACK (R4) path ----
#define F_WS_COUNTS 5120000u
#define F_WS_CURSOR 5160960u
#define F_WS_PERM   5201920u
#define F_WS_NEED   (5201920u + 1280000u)

typedef short s16x8 __attribute__((ext_vector_type(8)));
typedef float f32x4 __attribute__((ext_vector_type(4)));

union FragU { s16x8 v; unsigned u[4]; };

__device__ __forceinline__ unsigned cvt_pk_bf16(float lo, float hi) {
  unsigned r;
  asm("v_cvt_pk_bf16_f32 %0, %1, %2" : "=v"(r) : "v"(lo), "v"(hi));
  return r;
}
__device__ __forceinline__ float bf2f(unsigned short b) {
  union { unsigned u; float f; } v; v.u = ((unsigned)b) << 16; return v.f;
}
__device__ __forceinline__ float silu_f(float x) {
  float t = __builtin_amdgcn_exp2f(x * -1.44269504089f);
  return x * __builtin_amdgcn_rcpf(1.0f + t);
}
__device__ __forceinline__ void bar_lds() {
  asm volatile("s_waitcnt lgkmcnt(0)" ::: "memory");
  __builtin_amdgcn_sched_barrier(0);
  __builtin_amdgcn_s_barrier();
  __builtin_amdgcn_sched_barrier(0);
}
__device__ __forceinline__ void bar_all() {
  asm volatile("s_waitcnt vmcnt(0) lgkmcnt(0)" ::: "memory");
  __builtin_amdgcn_sched_barrier(0);
  __builtin_amdgcn_s_barrier();
  __builtin_amdgcn_sched_barrier(0);
}
__device__ __forceinline__ void wait_vm0() {
  asm volatile("s_waitcnt vmcnt(0)" ::: "memory");
  __builtin_amdgcn_sched_barrier(0);
}
__device__ __forceinline__ void gload_lds16(const unsigned short* g, char* l) {
  __builtin_amdgcn_global_load_lds(
      (const __attribute__((address_space(1))) unsigned int*)g,
      (__attribute__((address_space(3))) unsigned int*)l, 16, 0, 0);
}

// ================= prep: h -> bf16 (into d_out), zero agg + counts =================
__global__ __launch_bounds__(256)
void prep_kernel(const float* __restrict__ h, unsigned short* __restrict__ hbf,
                 float* __restrict__ agg, int* __restrict__ counts) {
  int g = blockIdx.x * 256 + threadIdx.x;
  int i = g * 4;
  if (i < N_NODES * D_F) {
    f32x4 v = *(const f32x4*)(h + i);
    *(unsigned*)(hbf + i)     = cvt_pk_bf16(v[0], v[1]);
    *(unsigned*)(hbf + i + 2) = cvt_pk_bf16(v[2], v[3]);
    *(f32x4*)(agg + i) = (f32x4){0.f, 0.f, 0.f, 0.f};
  }
  if (g < 10240) counts[g] = 0;
}

// ================= sort: histogram / scan / scatter =================
__global__ __launch_bounds__(256)
void hist_kernel(const int* __restrict__ ei, int* __restrict__ counts) {
  for (int e = blockIdx.x * 256 + threadIdx.x; e < N_EDGES; e += gridDim.x * 256)
    atomicAdd(&counts[ei[e]], 1);
}

__global__ __launch_bounds__(1024)
void scan_kernel(const int* __restrict__ counts, int* __restrict__ cursor) {
  __shared__ int sd[1024];
  const int t = threadIdx.x;
  const int base = t * 10;
  int loc[10]; int s = 0;
#pragma unroll
  for (int j = 0; j < 10; ++j) { loc[j] = counts[base + j]; s += loc[j]; }
  sd[t] = s;
  __syncthreads();
  for (int off = 1; off < 1024; off <<= 1) {
    int v = sd[t];
    int a = (t >= off) ? sd[t - off] : 0;
    __syncthreads();
    sd[t] = v + a;
    __syncthreads();
  }
  int run = sd[t] - s;
#pragma unroll
  for (int j = 0; j < 10; ++j) { cursor[base + j] = run; run += loc[j]; }
}

// full path: write sorted flat arrays directly (no perm)
__global__ __launch_bounds__(256)
void scatter2_kernel(const int* __restrict__ ei, const float* __restrict__ coord,
                     const float* __restrict__ edge_mask, int* __restrict__ cursor,
                     unsigned* __restrict__ rc, float2* __restrict__ radm) {
  for (int e = blockIdx.x * 256 + threadIdx.x; e < N_EDGES; e += gridDim.x * 256) {
    int r = ei[e], c = ei[N_EDGES + e];
    int pos = atomicAdd(&cursor[r], 1);
    float dx = coord[r * 3 + 0] - coord[c * 3 + 0];
    float dy = coord[r * 3 + 1] - coord[c * 3 + 1];
    float dz = coord[r * 3 + 2] - coord[c * 3 + 2];
    rc[pos] = (unsigned)r | ((unsigned)c << 16);
    radm[pos] = make_float2(dx * dx + dy * dy + dz * dz, edge_mask[e]);
  }
}

// fallback path scatter: perm only
__global__ __launch_bounds__(256)
void scatter_kernel(const int* __restrict__ ei, int* __restrict__ cursor,
                    int* __restrict__ perm) {
  for (int e = blockIdx.x * 256 + threadIdx.x; e < N_EDGES; e += gridDim.x * 256) {
    int r = ei[e];
    int p = atomicAdd(&cursor[r], 1);
    perm[p] = e;
  }
}

// ================= edge kernel (pipelined, DMA-staged) =================
// LDS map: A dbuf 2x32KB (k-major: [chunk 0..31][64 e][16B]) @0
//          M1 (16KB) and M2 (16KB) ALIAS the dead abuf_cur after GEMM1.
//          meta dbuf 2x768B @65536
// Wave mapping (R8): each wave owns 16 output cols (nt=1) x all 64 edges (mt=4)
//   -> weight fragments 48 VGPR (was 96), targeting total alloc ~100 so that
//      two 8-wave blocks fit per CU (needs <=128 incl. accumulator rounding).
#define OFF_META 65536u
#define EDGE_LDS 67072u

__global__ __launch_bounds__(512, 2)
void egcl_edge_kernel(const unsigned short* __restrict__ hbf,
                      const float* __restrict__ We1, const float* __restrict__ be1,
                      const float* __restrict__ We2, const float* __restrict__ be2,
                      const unsigned* __restrict__ rc, const float2* __restrict__ radm,
                      float* __restrict__ agg) {
  extern __shared__ __attribute__((aligned(16))) char smem[];
  const int tid  = threadIdx.x;
  const int lane = tid & 63;
  const int wv   = tid >> 6;          // 0..7 : col group of 16
  const int l15  = lane & 15;
  const int lg   = lane >> 4;
  const int col0 = wv * 16 + l15;

  // ---- per-wave weight fragments in registers (bf16), nt=1 ----
  FragU bw1[8];
  FragU bw2[4];
#pragma unroll
  for (int kt = 0; kt < 8; ++kt) {
    const int kb = kt * 32 + lg * 8;
#pragma unroll
    for (int j = 0; j < 4; ++j)
      bw1[kt].u[j] = cvt_pk_bf16(We1[(kb + 2 * j) * D_F + col0],
                                 We1[(kb + 2 * j + 1) * D_F + col0]);
  }
#pragma unroll
  for (int kt = 0; kt < 4; ++kt) {
    const int kb = kt * 32 + lg * 8;
#pragma unroll
    for (int j = 0; j < 4; ++j)
      bw2[kt].u[j] = cvt_pk_bf16(We2[(kb + 2 * j) * D_F + col0],
                                 We2[(kb + 2 * j + 1) * D_F + col0]);
  }
  const float bv1 = be1[col0];
  const float wlv = We1[256 * D_F + col0];
  const float bv2 = be2[col0];

  const int bid = (int)blockIdx.x;

  // ---- prologue: tile t0 ----
  int t = bid;
  unsigned crc; float2 crm;
  {
    crc = rc[t * TE + lane];
    crm = radm[t * TE + lane];
    if (tid < 64) {
      *(int*)(smem + OFF_META + 0 + tid * 4)     = (int)(crc & 0xFFFFu);
      *(float*)(smem + OFF_META + 256 + tid * 4) = crm.x;
      *(float*)(smem + OFF_META + 512 + tid * 4) = crm.y;
    }
    unsigned node = (wv < 4) ? (crc & 0xFFFFu) : (crc >> 16);
    const unsigned short* gsrc = hbf + (size_t)node * D_F;
    char* dst = smem;  // buf 0
#pragma unroll
    for (int k = 0; k < 4; ++k) {
      int c = wv * 4 + k;
      gload_lds16(gsrc + (c & 15) * 8, dst + c * 1024 + lane * 16);
    }
    int tn = t + GRID; int tnc = (tn < NTILES) ? tn : t;
    crc = rc[tnc * TE + lane];
    crm = radm[tnc * TE + lane];
  }
  bar_all();
  int p = 0;

  for (; t < NTILES; t += GRID) {
    char* abuf_cur = smem + p * 32768;
    char* abuf_nxt = smem + (p ^ 1) * 32768;
    char* m1base   = abuf_cur;            // aliases dead A after GEMM1
    char* m2base   = abuf_cur + 16384;
    const int mo = p * 768, mn = (p ^ 1) * 768;
    int*   rowsL = (int*)(smem + OFF_META + mo);
    float* radsL = (float*)(smem + OFF_META + mo + 256);
    float* msksL = (float*)(smem + OFF_META + mo + 512);

    // ---- P1: GEMM1 over A(t) : all 64 edges x 16 cols per wave ----
    f32x4 acc[4];
#pragma unroll
    for (int mt = 0; mt < 4; ++mt) acc[mt] = (f32x4){0.f, 0.f, 0.f, 0.f};
    __builtin_amdgcn_s_setprio(1);
#pragma unroll
    for (int ks = 0; ks < 8; ++ks) {
      s16x8 a[4];
      const int chunk = ks * 4 + lg;
#pragma unroll
      for (int mt = 0; mt < 4; ++mt)
        a[mt] = *(const s16x8*)(abuf_cur + chunk * 1024 + (mt * 16 + l15) * 16);
#pragma unroll
      for (int mt = 0; mt < 4; ++mt)
        acc[mt] = __builtin_amdgcn_mfma_f32_16x16x32_bf16(a[mt], bw1[ks].v,
                                                          acc[mt], 0, 0, 0);
    }
    __builtin_amdgcn_s_setprio(0);
    // A(t) fully consumed by all waves before M1/M2 overwrite it:
    bar_lds();

    // ---- ep1: +be1 +radial*wlast, silu -> M1 (aliases A) ----
#pragma unroll
    for (int mt = 0; mt < 4; ++mt)
#pragma unroll
      for (int q = 0; q < 4; ++q) {
        int e = mt * 16 + lg * 4 + q;
        float v = acc[mt][q] + bv1 + radsL[e] * wlv;
        v = silu_f(v);
        *(unsigned short*)(m1base + (unsigned)(e * 256) +
                           ((unsigned)(col0 * 2) ^ ((unsigned)((e & 7) << 4)))) =
            (unsigned short)cvt_pk_bf16(v, v);
      }
    bar_lds();

    // ---- P2: DMA A(t+1), write meta(t+1), prefetch meta(t+2) ----
    {
      unsigned node = (wv < 4) ? (crc & 0xFFFFu) : (crc >> 16);
      const unsigned short* gsrc = hbf + (size_t)node * D_F;
#pragma unroll
      for (int k = 0; k < 4; ++k) {
        int c = wv * 4 + k;
        gload_lds16(gsrc + (c & 15) * 8, abuf_nxt + c * 1024 + lane * 16);
      }
      if (tid < 64) {
        *(int*)(smem + OFF_META + mn + 0 + tid * 4)     = (int)(crc & 0xFFFFu);
        *(float*)(smem + OFF_META + mn + 256 + tid * 4) = crm.x;
        *(float*)(smem + OFF_META + mn + 512 + tid * 4) = crm.y;
      }
    }
    int t2 = t + 2 * GRID; int t2c = (t2 < NTILES) ? t2 : bid;
    unsigned nrc = rc[t2c * TE + lane];
    float2 nrm = radm[t2c * TE + lane];

    // ---- P4: GEMM2 over M1 ----
    f32x4 acc2[4];
#pragma unroll
    for (int mt = 0; mt < 4; ++mt) acc2[mt] = (f32x4){0.f, 0.f, 0.f, 0.f};
    const unsigned rswz = (unsigned)((l15 & 7) << 4);
    __builtin_amdgcn_s_setprio(1);
#pragma unroll
    for (int ks = 0; ks < 4; ++ks) {
      s16x8 a[4];
      unsigned kb = ((unsigned)((ks * 32 + lg * 8) * 2)) ^ rswz;
#pragma unroll
      for (int mt = 0; mt < 4; ++mt)
        a[mt] = *(const s16x8*)(m1base + (unsigned)((mt * 16 + l15) * 256) + kb);
#pragma unroll
      for (int mt = 0; mt < 4; ++mt)
        acc2[mt] = __builtin_amdgcn_mfma_f32_16x16x32_bf16(a[mt], bw2[ks].v,
                                                           acc2[mt], 0, 0, 0);
    }
    __builtin_amdgcn_s_setprio(0);
    // ---- ep2: silu*mask -> M2 ----
#pragma unroll
    for (int mt = 0; mt < 4; ++mt)
#pragma unroll
      for (int q = 0; q < 4; ++q) {
        int e = mt * 16 + lg * 4 + q;
        float v = silu_f(acc2[mt][q] + bv2) * msksL[e];
        *(unsigned short*)(m2base + (unsigned)(e * 256) +
                           ((unsigned)(col0 * 2) ^ ((unsigned)((e & 7) << 4)))) =
            (unsigned short)cvt_pk_bf16(v, v);
      }
    bar_lds();

    // ---- DMA drain BEFORE walk: everything outstanding is old -> ~free.
    //      The walk's atomics below are never waited on (end barrier is lgkm-only).
    wait_vm0();

    // ---- P6: segmented merge walk (16 edges per thread) ----
    {
      const int q4 = tid >> 7, colw = tid & 127;
      const int eb = q4 * 16;
      float a = 0.f;
      int cur = rowsL[eb];
#pragma unroll
      for (int i = 0; i < 16; ++i) {
        int e = eb + i;
        float v = bf2f(*(const unsigned short*)(
            m2base + (unsigned)(e * 256) +
            ((unsigned)(colw * 2) ^ ((unsigned)((e & 7) << 4)))));
        int r = rowsL[e];
        if (r != cur) {
          atomicAdd(agg + (size_t)cur * D_F + colw, a);
          a = 0.f; cur = r;
        }
        a += v;
      }
      atomicAdd(agg + (size_t)cur * D_F + colw, a);
    }
    // ---- end of tile: LDS-only barrier (atomics float across) ----
    bar_lds();
    crc = nrc; crm = nrm; p ^= 1;
  }
}

// ================= fallback edge kernel (R4, proven) =================
#define F_OFF_A    0u
#define F_OFF_M2   0u
#define F_OFF_M1   32768u
#define F_OFF_META 49152u
#define F_EDGE_LDS (49152u + 1024u)

template <bool SORTED>
__global__ __launch_bounds__(256)
void egcl_edge_fb(const float* __restrict__ h, const float* __restrict__ coord,
                  const float* __restrict__ edge_mask,
                  const float* __restrict__ We1, const float* __restrict__ be1,
                  const float* __restrict__ We2, const float* __restrict__ be2,
                  const int* __restrict__ ei, const int* __restrict__ perm,
                  float* __restrict__ agg) {
  extern __shared__ __attribute__((aligned(16))) char smem[];
  const int tid  = threadIdx.x;
  const int lane = tid & 63;
  const int wv   = tid >> 6;
  const int l15  = lane & 15;
  const int lg   = lane >> 4;
  const int c0   = wv * 32;
  const int col0 = c0 + l15;

  int*   rows = (int*)(smem + F_OFF_META);
  float* rads = (float*)(smem + F_OFF_META + 256);
  float* msks = (float*)(smem + F_OFF_META + 512);

  FragU bw1[8][2];
  FragU bw2[4][2];
#pragma unroll
  for (int kt = 0; kt < 8; ++kt)
#pragma unroll
    for (int nt = 0; nt < 2; ++nt) {
      const int col = col0 + nt * 16;
      const int kb = kt * 32 + lg * 8;
#pragma unroll
      for (int j = 0; j < 4; ++j)
        bw1[kt][nt].u[j] = cvt_pk_bf16(We1[(kb + 2 * j) * D_F + col],
                                       We1[(kb + 2 * j + 1) * D_F + col]);
    }
#pragma unroll
  for (int kt = 0; kt < 4; ++kt)
#pragma unroll
    for (int nt = 0; nt < 2; ++nt) {
      const int col = col0 + nt * 16;
      const int kb = kt * 32 + lg * 8;
#pragma unroll
      for (int j = 0; j < 4; ++j)
        bw2[kt][nt].u[j] = cvt_pk_bf16(We2[(kb + 2 * j) * D_F + col],
                                       We2[(kb + 2 * j + 1) * D_F + col]);
    }
  const float bv1[2] = {be1[col0], be1[col0 + 16]};
  const float wlv[2] = {We1[256 * D_F + col0], We1[256 * D_F + col0 + 16]};
  const float bv2[2] = {be2[col0], be2[col0 + 16]};

  const int se = tid >> 2;
  const int sq = tid & 3;
  const unsigned sswz = (unsigned)((se & 7) << 4);
  const unsigned rswz = (unsigned)((l15 & 7) << 4);

  for (int tile = (int)blockIdx.x; tile < NTILES; tile += (int)gridDim.x) {
    const int ebase = tile * TE;
    const int eidx = SORTED ? perm[ebase + se] : (ebase + se);
    const int n0 = ei[eidx];
    const int n1 = ei[N_EDGES + eidx];
    if (sq == 0) {
      float dx = coord[n0 * 3 + 0] - coord[n1 * 3 + 0];
      float dy = coord[n0 * 3 + 1] - coord[n1 * 3 + 1];
      float dz = coord[n0 * 3 + 2] - coord[n1 * 3 + 2];
      rows[se] = n0;
      rads[se] = dx * dx + dy * dy + dz * dz;
      msks[se] = edge_mask[eidx];
    }
#pragma unroll
    for (int pp = 0; pp < 2; ++pp) {
      const f32x4* src = (const f32x4*)(h + (pp ? n1 : n0) * D_F + sq * 32);
#pragma unroll
      for (int j = 0; j < 4; ++j) {
        f32x4 x0 = src[2 * j], x1 = src[2 * j + 1];
        FragU w;
        w.u[0] = cvt_pk_bf16(x0[0], x0[1]);
        w.u[1] = cvt_pk_bf16(x0[2], x0[3]);
        w.u[2] = cvt_pk_bf16(x1[0], x1[1]);
        w.u[3] = cvt_pk_bf16(x1[2], x1[3]);
        unsigned kb = (unsigned)(pp * 256 + sq * 64 + j * 16);
        *(s16x8*)(smem + F_OFF_A + (unsigned)(se * 512) + (kb ^ sswz)) = w.v;
      }
    }
    bar_lds();

    f32x4 acc[4][2];
#pragma unroll
    for (int mt = 0; mt < 4; ++mt)
#pragma unroll
      for (int nt = 0; nt < 2; ++nt) acc[mt][nt] = (f32x4){0.f, 0.f, 0.f, 0.f};
#pragma unroll
    for (int ks = 0; ks < 8; ++ks) {
      s16x8 a[4];
      unsigned kb = ((unsigned)((ks * 32 + lg * 8) * 2)) ^ rswz;
#pragma unroll
      for (int mt = 0; mt < 4; ++mt)
        a[mt] = *(const s16x8*)(smem + F_OFF_A + (unsigned)((mt * 16 + l15) * 512) + kb);
#pragma unroll
      for (int mt = 0; mt < 4; ++mt)
#pragma unroll
        for (int nt = 0; nt < 2; ++nt)
          acc[mt][nt] = __builtin_amdgcn_mfma_f32_16x16x32_bf16(a[mt], bw1[ks][nt].v,
                                                                acc[mt][nt], 0, 0, 0);
    }
#pragma unroll
    for (int mt = 0; mt < 4; ++mt)
#pragma unroll
      for (int nt = 0; nt < 2; ++nt)
#pragma unroll
        for (int q = 0; q < 4; ++q) {
          int e = mt * 16 + lg * 4 + q;
          float v = acc[mt][nt][q] + bv1[nt] + rads[e] * wlv[nt];
          v = silu_f(v);
          *(unsigned short*)(smem + F_OFF_M1 + (unsigned)(e * 256) +
                             ((unsigned)((c0 + nt * 16 + l15) * 2) ^
                              ((unsigned)((e & 7) << 4)))) =
              (unsigned short)cvt_pk_bf16(v, v);
        }
    bar_lds();

#pragma unroll
    for (int mt = 0; mt < 4; ++mt)
#pragma unroll
      for (int nt = 0; nt < 2; ++nt) acc[mt][nt] = (f32x4){0.f, 0.f, 0.f, 0.f};
#pragma unroll
    for (int ks = 0; ks < 4; ++ks) {
      s16x8 a[4];
      unsigned kb = ((unsigned)((ks * 32 + lg * 8) * 2)) ^ rswz;
#pragma unroll
      for (int mt = 0; mt < 4; ++mt)
        a[mt] = *(const s16x8*)(smem + F_OFF_M1 + (unsigned)((mt * 16 + l15) * 256) + kb);
#pragma unroll
      for (int mt = 0; mt < 4; ++mt)
#pragma unroll
        for (int nt = 0; nt < 2; ++nt)
          acc[mt][nt] = __builtin_amdgcn_mfma_f32_16x16x32_bf16(a[mt], bw2[ks][nt].v,
                                                                acc[mt][nt], 0, 0, 0);
    }
    if (SORTED) {
#pragma unroll
      for (int mt = 0; mt < 4; ++mt)
#pragma unroll
        for (int nt = 0; nt < 2; ++nt)
#pragma unroll
          for (int q = 0; q < 4; ++q) {
            int e = mt * 16 + lg * 4 + q;
            float v = silu_f(acc[mt][nt][q] + bv2[nt]) * msks[e];
            int col = c0 + nt * 16 + l15;
            *(unsigned short*)(smem + F_OFF_M2 + (unsigned)(e * 256) +
                               ((unsigned)(col * 2) ^ ((unsigned)((e & 7) << 4)))) =
                (unsigned short)cvt_pk_bf16(v, v);
          }
      bar_lds();
      {
        const int colw = tid & 127, half = tid >> 7;
        float a = 0.f;
        int cur = rows[half * 32];
#pragma unroll 8
        for (int i = 0; i < 32; ++i) {
          int e = half * 32 + i;
          float v = bf2f(*(const unsigned short*)(
              smem + F_OFF_M2 + (unsigned)(e * 256) +
              ((unsigned)(colw * 2) ^ ((unsigned)((e & 7) << 4)))));
          int r = rows[e];
          if (r != cur) { atomicAdd(agg + (size_t)cur * D_F + colw, a); a = 0.f; cur = r; }
          a += v;
        }
        atomicAdd(agg + (size_t)cur * D_F + colw, a);
      }
    } else {
#pragma unroll
      for (int mt = 0; mt < 4; ++mt)
#pragma unroll
        for (int q = 0; q < 4; ++q) {
          int e = mt * 16 + lg * 4 + q;
          int r = rows[e];
          float mk = msks[e];
#pragma unroll
          for (int nt = 0; nt < 2; ++nt) {
            float v = silu_f(acc[mt][nt][q] + bv2[nt]) * mk;
            atomicAdd(agg + (size_t)r * D_F + c0 + nt * 16 + l15, v);
          }
        }
    }
    bar_lds();
  }
}

// ================= node kernel (MFMA, residual) =================
#define NOFF_A  0u
#define NOFF_M1 32768u
#define NODE_LDS 49152u

__global__ __launch_bounds__(256)
void egcl_node_kernel(const float* __restrict__ h, const float* __restrict__ agg,
                      const float* __restrict__ Wn1, const float* __restrict__ bn1,
                      const float* __restrict__ Wn2, const float* __restrict__ bn2,
                      float* __restrict__ out) {
  extern __shared__ __attribute__((aligned(16))) char smem[];
  const int tid  = threadIdx.x;
  const int lane = tid & 63;
  const int wv   = tid >> 6;
  const int l15  = lane & 15;
  const int lg   = lane >> 4;
  const int c0   = wv * 32;
  const int col0 = c0 + l15;
  const int base = blockIdx.x * 64;

  FragU bw1[8][2];
  FragU bw2[4][2];
#pragma unroll
  for (int kt = 0; kt < 8; ++kt)
#pragma unroll
    for (int nt = 0; nt < 2; ++nt) {
      const int col = col0 + nt * 16;
      const int kb = kt * 32 + lg * 8;
#pragma unroll
      for (int j = 0; j < 4; ++j)
        bw1[kt][nt].u[j] = cvt_pk_bf16(Wn1[(kb + 2 * j) * D_F + col],
                                       Wn1[(kb + 2 * j + 1) * D_F + col]);
    }
#pragma unroll
  for (int kt = 0; kt < 4; ++kt)
#pragma unroll
    for (int nt = 0; nt < 2; ++nt) {
      const int col = col0 + nt * 16;
      const int kb = kt * 32 + lg * 8;
#pragma unroll
      for (int j = 0; j < 4; ++j)
        bw2[kt][nt].u[j] = cvt_pk_bf16(Wn2[(kb + 2 * j) * D_F + col],
                                       Wn2[(kb + 2 * j + 1) * D_F + col]);
    }
  const float bv1[2] = {bn1[col0], bn1[col0 + 16]};
  const float bv2[2] = {bn2[col0], bn2[col0 + 16]};

  const int se = tid >> 2;
  const int sq = tid & 3;
  const unsigned sswz = (unsigned)((se & 7) << 4);
  const unsigned rswz = (unsigned)((l15 & 7) << 4);
  const int node = base + se;

#pragma unroll
  for (int p = 0; p < 2; ++p) {
    FragU w;
    if (node < N_NODES) {
      const f32x4* src = (const f32x4*)((p ? agg : h) + node * D_F + sq * 32);
#pragma unroll
      for (int j = 0; j < 4; ++j) {
        f32x4 x0 = src[2 * j], x1 = src[2 * j + 1];
        w.u[0] = cvt_pk_bf16(x0[0], x0[1]);
        w.u[1] = cvt_pk_bf16(x0[2], x0[3]);
        w.u[2] = cvt_pk_bf16(x1[0], x1[1]);
        w.u[3] = cvt_pk_bf16(x1[2], x1[3]);
        unsigned kb = (unsigned)(p * 256 + sq * 64 + j * 16);
        *(s16x8*)(smem + NOFF_A + (unsigned)(se * 512) + (kb ^ sswz)) = w.v;
      }
    } else {
      w.u[0] = w.u[1] = w.u[2] = w.u[3] = 0u;
#pragma unroll
      for (int j = 0; j < 4; ++j) {
        unsigned kb = (unsigned)(p * 256 + sq * 64 + j * 16);
        *(s16x8*)(smem + NOFF_A + (unsigned)(se * 512) + (kb ^ sswz)) = w.v;
      }
    }
  }
  bar_lds();

  f32x4 acc[4][2];
#pragma unroll
  for (int mt = 0; mt < 4; ++mt)
#pragma unroll
    for (int nt = 0; nt < 2; ++nt) acc[mt][nt] = (f32x4){0.f, 0.f, 0.f, 0.f};
#pragma unroll
  for (int ks = 0; ks < 8; ++ks) {
    s16x8 a[4];
    unsigned kb = ((unsigned)((ks * 32 + lg * 8) * 2)) ^ rswz;
#pragma unroll
    for (int mt = 0; mt < 4; ++mt)
      a[mt] = *(const s16x8*)(smem + NOFF_A + (unsigned)((mt * 16 + l15) * 512) + kb);
#pragma unroll
    for (int mt = 0; mt < 4; ++mt)
#pragma unroll
      for (int nt = 0; nt < 2; ++nt)
        acc[mt][nt] = __builtin_amdgcn_mfma_f32_16x16x32_bf16(a[mt], bw1[ks][nt].v,
                                                              acc[mt][nt], 0, 0, 0);
  }
#pragma unroll
  for (int mt = 0; mt < 4; ++mt)
#pragma unroll
    for (int nt = 0; nt < 2; ++nt)
#pragma unroll
      for (int q = 0; q < 4; ++q) {
        int e = mt * 16 + lg * 4 + q;
        float v = silu_f(acc[mt][nt][q] + bv1[nt]);
        *(unsigned short*)(smem + NOFF_M1 + (unsigned)(e * 256) +
                           ((unsigned)((c0 + nt * 16 + l15) * 2) ^
                            ((unsigned)((e & 7) << 4)))) =
            (unsigned short)cvt_pk_bf16(v, v);
      }
  bar_lds();

#pragma unroll
  for (int mt = 0; mt < 4; ++mt)
#pragma unroll
    for (int nt = 0; nt < 2; ++nt) acc[mt][nt] = (f32x4){0.f, 0.f, 0.f, 0.f};
#pragma unroll
  for (int ks = 0; ks < 4; ++ks) {
    s16x8 a[4];
    unsigned kb = ((unsigned)((ks * 32 + lg * 8) * 2)) ^ rswz;
#pragma unroll
    for (int mt = 0; mt < 4; ++mt)
      a[mt] = *(const s16x8*)(smem + NOFF_M1 + (unsigned)((mt * 16 + l15) * 256) + kb);
#pragma unroll
    for (int mt = 0; mt < 4; ++mt)
#pragma unroll
      for (int nt = 0; nt < 2; ++nt)
        acc[mt][nt] = __builtin_amdgcn_mfma_f32_16x16x32_bf16(a[mt], bw2[ks][nt].v,
                                                              acc[mt][nt], 0, 0, 0);
  }
#pragma unroll
  for (int mt = 0; mt < 4; ++mt)
#pragma unroll
    for (int q = 0; q < 4; ++q) {
      int nd = base + mt * 16 + lg * 4 + q;
      if (nd < N_NODES) {
#pragma unroll
        for (int nt = 0; nt < 2; ++nt) {
          int col = c0 + nt * 16 + l15;
          out[nd * D_F + col] = h[nd * D_F + col] + acc[mt][nt][q] + bv2[nt];
        }
      }
    }
}

extern "C" void kernel_launch(void* const* d_in, const int* in_sizes, int n_in,
                              void* d_out, int out_size, void* d_ws, size_t ws_size,
                              hipStream_t stream) {
  (void)in_sizes; (void)n_in; (void)out_size;
  const float* h         = (const float*)d_in[0];
  const float* coord     = (const float*)d_in[1];
  const float* edge_mask = (const float*)d_in[2];
  const float* We1       = (const float*)d_in[3];
  const float* be1       = (const float*)d_in[4];
  const float* We2       = (const float*)d_in[5];
  const float* be2       = (const float*)d_in[6];
  const float* Wn1       = (const float*)d_in[7];
  const float* bn1       = (const float*)d_in[8];
  const float* Wn2       = (const float*)d_in[9];
  const float* bn2       = (const float*)d_in[10];
  const int*   ei        = (const int*)d_in[11];
  float* out = (float*)d_out;
  char* ws = (char*)d_ws;
  float* agg = (float*)(ws + WS_AGG);

  hipFuncSetAttribute((const void*)egcl_edge_kernel,
                      hipFuncAttributeMaxDynamicSharedMemorySize, (int)EDGE_LDS);
  hipFuncSetAttribute((const void*)egcl_node_kernel,
                      hipFuncAttributeMaxDynamicSharedMemorySize, (int)NODE_LDS);

  if (ws_size >= (size_t)WS_FULL_NEED) {
    unsigned* rcarr  = (unsigned*)(ws + WS_RC);
    float2*   radm   = (float2*)(ws + WS_RADM);
    int*      counts = (int*)(ws + WS_COUNTS);
    int*      cursor = (int*)(ws + WS_CURSOR);
    unsigned short* hbf = (unsigned short*)d_out;  // scratch; node kernel overwrites later

    prep_kernel<<<(N_NODES * D_F / 4 + 255) / 256, 256, 0, stream>>>(h, hbf, agg, counts);
    hist_kernel<<<512, 256, 0, stream>>>(ei, counts);
    scan_kernel<<<1, 1024, 0, stream>>>(counts, cursor);
    scatter2_kernel<<<512, 256, 0, stream>>>(ei, coord, edge_mask, cursor, rcarr, radm);
    egcl_edge_kernel<<<GRID, 512, EDGE_LDS, stream>>>(
        hbf, We1, be1, We2, be2, rcarr, radm, agg);
  } else if (ws_size >= (size_t)F_WS_NEED) {
    int* counts = (int*)(ws + F_WS_COUNTS);
    int* cursor = (int*)(ws + F_WS_CURSOR);
    int* perm   = (int*)(ws + F_WS_PERM);
    hipFuncSetAttribute((const void*)egcl_edge_fb<true>,
                        hipFuncAttributeMaxDynamicSharedMemorySize, (int)F_EDGE_LDS);
    hipMemsetAsync(ws, 0, F_WS_CURSOR, stream);
    hist_kernel<<<512, 256, 0, stream>>>(ei, counts);
    scan_kernel<<<1, 1024, 0, stream>>>(counts, cursor);
    scatter_kernel<<<512, 256, 0, stream>>>(ei, cursor, perm);
    egcl_edge_fb<true><<<768, 256, F_EDGE_LDS, stream>>>(
        h, coord, edge_mask, We1, be1, We2, be2, ei, perm, agg);
  } else {
    hipFuncSetAttribute((const void*)egcl_edge_fb<false>,
                        hipFuncAttributeMaxDynamicSharedMemorySize, (int)F_EDGE_LDS);
    hipMemsetAsync(agg, 0, (size_t)N_NODES * D_F * sizeof(float), stream);
    egcl_edge_fb<false><<<768, 256, F_EDGE_LDS, stream>>>(
        h, coord, edge_mask, We1, be1, We2, be2, ei, nullptr, agg);
  }
  egcl_node_kernel<<<(N_NODES + 63) / 64, 256, NODE_LDS, stream>>>(
      h, agg, Wn1, bn1, Wn2, bn2, out);
}

// Round 9
// 143.360 us; speedup vs baseline: 1.7583x; 1.0936x over previous
//
#include <hip/hip_runtime.h>

#define D_F 128
#define N_NODES 10000
#define N_EDGES 320000

// ---- workspace layout: FULL path ----
#define WS_AGG       0u
#define WS_RC        5120000u                  // E uints  (row | col<<16)
#define WS_RADM      6400000u                  // E float2 (radial, mask)
#define WS_COUNTS    8960000u                  // 10240 ints
#define WS_CURSOR    9000960u                  // 10240 ints
#define WS_FULL_NEED 9041920u

// ---- workspace layout: FALLBACK (R4) path ----
#define F_WS_COUNTS 5120000u
#define F_WS_CURSOR 5160960u
#define F_WS_PERM   5201920u
#define F_WS_NEED   (5201920u + 1280000u)

typedef short s16x8 __attribute__((ext_vector_type(8)));
typedef float f32x4 __attribute__((ext_vector_type(4)));

union FragU { s16x8 v; unsigned u[4]; };

__device__ __forceinline__ unsigned cvt_pk_bf16(float lo, float hi) {
  unsigned r;
  asm("v_cvt_pk_bf16_f32 %0, %1, %2" : "=v"(r) : "v"(lo), "v"(hi));
  return r;
}
__device__ __forceinline__ float bf2f(unsigned short b) {
  union { unsigned u; float f; } v; v.u = ((unsigned)b) << 16; return v.f;
}
__device__ __forceinline__ float silu_f(float x) {
  float t = __builtin_amdgcn_exp2f(x * -1.44269504089f);
  return x * __builtin_amdgcn_rcpf(1.0f + t);
}
__device__ __forceinline__ void bar_lds() {
  asm volatile("s_waitcnt lgkmcnt(0)" ::: "memory");
  __builtin_amdgcn_sched_barrier(0);
  __builtin_amdgcn_s_barrier();
  __builtin_amdgcn_sched_barrier(0);
}
__device__ __forceinline__ void bar_all() {
  asm volatile("s_waitcnt vmcnt(0) lgkmcnt(0)" ::: "memory");
  __builtin_amdgcn_sched_barrier(0);
  __builtin_amdgcn_s_barrier();
  __builtin_amdgcn_sched_barrier(0);
}
__device__ __forceinline__ void wait_vm0() {
  asm volatile("s_waitcnt vmcnt(0)" ::: "memory");
  __builtin_amdgcn_sched_barrier(0);
}
__device__ __forceinline__ void gload_lds16(const unsigned short* g, char* l) {
  __builtin_amdgcn_global_load_lds(
      (const __attribute__((address_space(1))) unsigned int*)g,
      (__attribute__((address_space(3))) unsigned int*)l, 16, 0, 0);
}

// ================= prep: h -> bf16 (into d_out), zero agg + counts =================
__global__ __launch_bounds__(256)
void prep_kernel(const float* __restrict__ h, unsigned short* __restrict__ hbf,
                 float* __restrict__ agg, int* __restrict__ counts) {
  int g = blockIdx.x * 256 + threadIdx.x;
  int i = g * 4;
  if (i < N_NODES * D_F) {
    f32x4 v = *(const f32x4*)(h + i);
    *(unsigned*)(hbf + i)     = cvt_pk_bf16(v[0], v[1]);
    *(unsigned*)(hbf + i + 2) = cvt_pk_bf16(v[2], v[3]);
    *(f32x4*)(agg + i) = (f32x4){0.f, 0.f, 0.f, 0.f};
  }
  if (g < 10240) counts[g] = 0;
}

// ================= sort: histogram / scan / scatter =================
__global__ __launch_bounds__(256)
void hist_kernel(const int* __restrict__ ei, int* __restrict__ counts) {
  for (int e = blockIdx.x * 256 + threadIdx.x; e < N_EDGES; e += gridDim.x * 256)
    atomicAdd(&counts[ei[e]], 1);
}

__global__ __launch_bounds__(1024)
void scan_kernel(const int* __restrict__ counts, int* __restrict__ cursor) {
  __shared__ int sd[1024];
  const int t = threadIdx.x;
  const int base = t * 10;
  int loc[10]; int s = 0;
#pragma unroll
  for (int j = 0; j < 10; ++j) { loc[j] = counts[base + j]; s += loc[j]; }
  sd[t] = s;
  __syncthreads();
  for (int off = 1; off < 1024; off <<= 1) {
    int v = sd[t];
    int a = (t >= off) ? sd[t - off] : 0;
    __syncthreads();
    sd[t] = v + a;
    __syncthreads();
  }
  int run = sd[t] - s;
#pragma unroll
  for (int j = 0; j < 10; ++j) { cursor[base + j] = run; run += loc[j]; }
}

// full path: write sorted flat arrays directly (no perm)
__global__ __launch_bounds__(256)
void scatter2_kernel(const int* __restrict__ ei, const float* __restrict__ coord,
                     const float* __restrict__ edge_mask, int* __restrict__ cursor,
                     unsigned* __restrict__ rc, float2* __restrict__ radm) {
  for (int e = blockIdx.x * 256 + threadIdx.x; e < N_EDGES; e += gridDim.x * 256) {
    int r = ei[e], c = ei[N_EDGES + e];
    int pos = atomicAdd(&cursor[r], 1);
    float dx = coord[r * 3 + 0] - coord[c * 3 + 0];
    float dy = coord[r * 3 + 1] - coord[c * 3 + 1];
    float dz = coord[r * 3 + 2] - coord[c * 3 + 2];
    rc[pos] = (unsigned)r | ((unsigned)c << 16);
    radm[pos] = make_float2(dx * dx + dy * dy + dz * dz, edge_mask[e]);
  }
}

// fallback path scatter: perm only
__global__ __launch_bounds__(256)
void scatter_kernel(const int* __restrict__ ei, int* __restrict__ cursor,
                    int* __restrict__ perm) {
  for (int e = blockIdx.x * 256 + threadIdx.x; e < N_EDGES; e += gridDim.x * 256) {
    int r = ei[e];
    int p = atomicAdd(&cursor[r], 1);
    perm[p] = e;
  }
}

// ================= edge kernel v2: 256-thr / 4-wave blocks, TE=32 =================
// Rationale (R9): 512-thr monolithic block never co-schedules a 2nd block
// (R7/R8: occupancy pinned at 1 block regardless of VGPR 88-112). Two 4-wave
// blocks at ~49KB LDS each = 2 independent barrier domains per CU.
// LDS: A dbuf 2x16KB (k-major: [pair 0..15][1KB: chunk lo 32e x16B | chunk hi]) @0
//      M1 [32e][128k] bf16 swz @32768 (8KB) ; M2 [32e][128col] @40960 (8KB)
//      meta dbuf 2x512B @49152
#define TE2   32
#define GRID2 512
#define NT2   (N_EDGES / TE2)   // 10000
#define E2_M1   32768u
#define E2_M2   40960u
#define E2_META 49152u
#define E2_LDS  50176u

__global__ __launch_bounds__(256)
void egcl_edge2(const unsigned short* __restrict__ hbf,
                const float* __restrict__ We1, const float* __restrict__ be1,
                const float* __restrict__ We2, const float* __restrict__ be2,
                const unsigned* __restrict__ rc, const float2* __restrict__ radm,
                float* __restrict__ agg) {
  extern __shared__ __attribute__((aligned(16))) char smem[];
  const int tid  = threadIdx.x;
  const int lane = tid & 63;
  const int wv   = tid >> 6;          // 0..3 : col group of 32
  const int l15  = lane & 15;
  const int lg   = lane >> 4;
  const int c0   = wv * 32;
  const int col0 = c0 + l15;
  const int le   = lane & 31;         // edge index this lane tracks
  const int lh   = lane >> 5;         // chunk parity within DMA pair

  // ---- per-wave weight fragments in registers (bf16) : 32 cols/wave ----
  FragU bw1[8][2];
  FragU bw2[4][2];
#pragma unroll
  for (int kt = 0; kt < 8; ++kt)
#pragma unroll
    for (int nt = 0; nt < 2; ++nt) {
      const int col = col0 + nt * 16;
      const int kb = kt * 32 + lg * 8;
#pragma unroll
      for (int j = 0; j < 4; ++j)
        bw1[kt][nt].u[j] = cvt_pk_bf16(We1[(kb + 2 * j) * D_F + col],
                                       We1[(kb + 2 * j + 1) * D_F + col]);
    }
#pragma unroll
  for (int kt = 0; kt < 4; ++kt)
#pragma unroll
    for (int nt = 0; nt < 2; ++nt) {
      const int col = col0 + nt * 16;
      const int kb = kt * 32 + lg * 8;
#pragma unroll
      for (int j = 0; j < 4; ++j)
        bw2[kt][nt].u[j] = cvt_pk_bf16(We2[(kb + 2 * j) * D_F + col],
                                       We2[(kb + 2 * j + 1) * D_F + col]);
    }
  const float bv1[2] = {be1[col0], be1[col0 + 16]};
  const float wlv[2] = {We1[256 * D_F + col0], We1[256 * D_F + col0 + 16]};
  const float bv2[2] = {be2[col0], be2[col0 + 16]};
  const unsigned rswz = (unsigned)((l15 & 7) << 4);

  const int bid = (int)blockIdx.x;
  int t = bid;
  unsigned crc; float2 crm;

  // ---- prologue: stage tile t0 into buf0, prefetch meta(t1) ----
  {
    crc = rc[t * TE2 + le];
    crm = radm[t * TE2 + le];
    if (tid < 32) {
      *(int*)(smem + E2_META + 0 + tid * 4)     = (int)(crc & 0xFFFFu);
      *(float*)(smem + E2_META + 128 + tid * 4) = crm.x;
      *(float*)(smem + E2_META + 256 + tid * 4) = crm.y;
    }
#pragma unroll
    for (int k = 0; k < 4; ++k) {
      int pr = wv * 4 + k;              // pair 0..15 -> chunks 2pr, 2pr+1
      int cc = 2 * pr + lh;             // chunk 0..31 (k-slice of 8 bf16)
      unsigned node = (cc < 16) ? (crc & 0xFFFFu) : (crc >> 16);
      gload_lds16(hbf + (size_t)node * D_F + (cc & 15) * 8,
                  smem + pr * 1024 + lane * 16);
    }
    int tn = t + GRID2; int tnc = (tn < NT2) ? tn : t;
    crc = rc[tnc * TE2 + le];
    crm = radm[tnc * TE2 + le];
  }
  bar_all();
  int p = 0;

  for (; t < NT2; t += GRID2) {
    char* cur = smem + p * 16384;
    char* nxt = smem + (p ^ 1) * 16384;
    const int mo = p * 512, mn = (p ^ 1) * 512;
    int*   rowsL = (int*)(smem + E2_META + mo);
    float* radsL = (float*)(smem + E2_META + mo + 128);
    float* msksL = (float*)(smem + E2_META + mo + 256);

    // ---- step0: DMA A(t+1) -> nxt (overlaps the whole tile), meta(t+1) -> mn ----
    // Hazards: nxt fully consumed by GEMM1(t-1) [pre B1(t-1)]; mn's old content
    // consumed by walk(t-1) [pre B3(t-1)]. Both barriers already passed.
    {
#pragma unroll
      for (int k = 0; k < 4; ++k) {
        int pr = wv * 4 + k;
        int cc = 2 * pr + lh;
        unsigned node = (cc < 16) ? (crc & 0xFFFFu) : (crc >> 16);
        gload_lds16(hbf + (size_t)node * D_F + (cc & 15) * 8,
                    nxt + pr * 1024 + lane * 16);
      }
      if (tid < 32) {
        *(int*)(smem + E2_META + mn + 0 + tid * 4)     = (int)(crc & 0xFFFFu);
        *(float*)(smem + E2_META + mn + 128 + tid * 4) = crm.x;
        *(float*)(smem + E2_META + mn + 256 + tid * 4) = crm.y;
      }
    }
    int t2 = t + 2 * GRID2; int t2c = (t2 < NT2) ? t2 : bid;
    unsigned nrc = rc[t2c * TE2 + le];
    float2 nrm = radm[t2c * TE2 + le];

    // ---- GEMM1 over A(t): 32 edges x 32 cols/wave ----
    f32x4 acc[2][2];
#pragma unroll
    for (int mt = 0; mt < 2; ++mt)
#pragma unroll
      for (int nt = 0; nt < 2; ++nt) acc[mt][nt] = (f32x4){0.f, 0.f, 0.f, 0.f};
    __builtin_amdgcn_s_setprio(1);
#pragma unroll
    for (int ks = 0; ks < 8; ++ks) {
      s16x8 a[2];
      const int chunk = ks * 4 + lg;
#pragma unroll
      for (int mt = 0; mt < 2; ++mt)
        a[mt] = *(const s16x8*)(cur + chunk * 512 + (mt * 16 + l15) * 16);
#pragma unroll
      for (int mt = 0; mt < 2; ++mt)
#pragma unroll
        for (int nt = 0; nt < 2; ++nt)
          acc[mt][nt] = __builtin_amdgcn_mfma_f32_16x16x32_bf16(a[mt], bw1[ks][nt].v,
                                                                acc[mt][nt], 0, 0, 0);
    }
    __builtin_amdgcn_s_setprio(0);

    // ---- ep1: +be1 +radial*wlast, silu -> M1 (no barrier: M1 dead since B2(t-1)) ----
#pragma unroll
    for (int mt = 0; mt < 2; ++mt)
#pragma unroll
      for (int nt = 0; nt < 2; ++nt)
#pragma unroll
        for (int q = 0; q < 4; ++q) {
          int e = mt * 16 + lg * 4 + q;
          float v = acc[mt][nt][q] + bv1[nt] + radsL[e] * wlv[nt];
          v = silu_f(v);
          *(unsigned short*)(smem + E2_M1 + (unsigned)(e * 256) +
                             ((unsigned)((c0 + nt * 16 + l15) * 2) ^
                              ((unsigned)((e & 7) << 4)))) =
              (unsigned short)cvt_pk_bf16(v, v);
        }
    bar_lds();  // B1: M1 visible to all waves

    // ---- GEMM2 over M1 ----
    f32x4 acc2[2][2];
#pragma unroll
    for (int mt = 0; mt < 2; ++mt)
#pragma unroll
      for (int nt = 0; nt < 2; ++nt) acc2[mt][nt] = (f32x4){0.f, 0.f, 0.f, 0.f};
    __builtin_amdgcn_s_setprio(1);
#pragma unroll
    for (int ks = 0; ks < 4; ++ks) {
      s16x8 a[2];
      unsigned kb = ((unsigned)((ks * 32 + lg * 8) * 2)) ^ rswz;
#pragma unroll
      for (int mt = 0; mt < 2; ++mt)
        a[mt] = *(const s16x8*)(smem + E2_M1 +
                                (unsigned)((mt * 16 + l15) * 256) + kb);
#pragma unroll
      for (int mt = 0; mt < 2; ++mt)
#pragma unroll
        for (int nt = 0; nt < 2; ++nt)
          acc2[mt][nt] = __builtin_amdgcn_mfma_f32_16x16x32_bf16(a[mt], bw2[ks][nt].v,
                                                                 acc2[mt][nt], 0, 0, 0);
    }
    __builtin_amdgcn_s_setprio(0);
    // ---- ep2: silu*mask -> M2 ----
#pragma unroll
    for (int mt = 0; mt < 2; ++mt)
#pragma unroll
      for (int nt = 0; nt < 2; ++nt)
#pragma unroll
        for (int q = 0; q < 4; ++q) {
          int e = mt * 16 + lg * 4 + q;
          float v = silu_f(acc2[mt][nt][q] + bv2[nt]) * msksL[e];
          int col = c0 + nt * 16 + l15;
          *(unsigned short*)(smem + E2_M2 + (unsigned)(e * 256) +
                             ((unsigned)(col * 2) ^ ((unsigned)((e & 7) << 4)))) =
              (unsigned short)cvt_pk_bf16(v, v);
        }
    bar_lds();  // B2: M2 visible; M1 free for next tile

    // drain own DMAs + meta prefetch (old by now -> ~free); barrier B3 below
    // then guarantees all waves' DMAs landed before next GEMM1.
    wait_vm0();

    // ---- walk: 2 threads/col x 16 edges, one atomic per row-run ----
    {
      const int q4 = tid >> 7, colw = tid & 127;
      const int eb = q4 * 16;
      float a = 0.f;
      int curR = rowsL[eb];
#pragma unroll
      for (int i = 0; i < 16; ++i) {
        int e = eb + i;
        float v = bf2f(*(const unsigned short*)(
            smem + E2_M2 + (unsigned)(e * 256) +
            ((unsigned)(colw * 2) ^ ((unsigned)((e & 7) << 4)))));
        int r = rowsL[e];
        if (r != curR) {
          atomicAdd(agg + (size_t)curR * D_F + colw, a);
          a = 0.f; curR = r;
        }
        a += v;
      }
      atomicAdd(agg + (size_t)curR * D_F + colw, a);
    }
    bar_lds();  // B3 (lgkm-only: atomics float across)
    crc = nrc; crm = nrm; p ^= 1;
  }
}

// ================= fallback edge kernel (R4, proven) =================
#define F_OFF_A    0u
#define F_OFF_M2   0u
#define F_OFF_M1   32768u
#define F_OFF_META 49152u
#define F_EDGE_LDS (49152u + 1024u)
#define NTILES (N_EDGES / 64)

template <bool SORTED>
__global__ __launch_bounds__(256)
void egcl_edge_fb(const float* __restrict__ h, const float* __restrict__ coord,
                  const float* __restrict__ edge_mask,
                  const float* __restrict__ We1, const float* __restrict__ be1,
                  const float* __restrict__ We2, const float* __restrict__ be2,
                  const int* __restrict__ ei, const int* __restrict__ perm,
                  float* __restrict__ agg) {
  extern __shared__ __attribute__((aligned(16))) char smem[];
  const int tid  = threadIdx.x;
  const int lane = tid & 63;
  const int wv   = tid >> 6;
  const int l15  = lane & 15;
  const int lg   = lane >> 4;
  const int c0   = wv * 32;
  const int col0 = c0 + l15;

  int*   rows = (int*)(smem + F_OFF_META);
  float* rads = (float*)(smem + F_OFF_META + 256);
  float* msks = (float*)(smem + F_OFF_META + 512);

  FragU bw1[8][2];
  FragU bw2[4][2];
#pragma unroll
  for (int kt = 0; kt < 8; ++kt)
#pragma unroll
    for (int nt = 0; nt < 2; ++nt) {
      const int col = col0 + nt * 16;
      const int kb = kt * 32 + lg * 8;
#pragma unroll
      for (int j = 0; j < 4; ++j)
        bw1[kt][nt].u[j] = cvt_pk_bf16(We1[(kb + 2 * j) * D_F + col],
                                       We1[(kb + 2 * j + 1) * D_F + col]);
    }
#pragma unroll
  for (int kt = 0; kt < 4; ++kt)
#pragma unroll
    for (int nt = 0; nt < 2; ++nt) {
      const int col = col0 + nt * 16;
      const int kb = kt * 32 + lg * 8;
#pragma unroll
      for (int j = 0; j < 4; ++j)
        bw2[kt][nt].u[j] = cvt_pk_bf16(We2[(kb + 2 * j) * D_F + col],
                                       We2[(kb + 2 * j + 1) * D_F + col]);
    }
  const float bv1[2] = {be1[col0], be1[col0 + 16]};
  const float wlv[2] = {We1[256 * D_F + col0], We1[256 * D_F + col0 + 16]};
  const float bv2[2] = {be2[col0], be2[col0 + 16]};

  const int se = tid >> 2;
  const int sq = tid & 3;
  const unsigned sswz = (unsigned)((se & 7) << 4);
  const unsigned rswz = (unsigned)((l15 & 7) << 4);

  for (int tile = (int)blockIdx.x; tile < NTILES; tile += (int)gridDim.x) {
    const int ebase = tile * 64;
    const int eidx = SORTED ? perm[ebase + se] : (ebase + se);
    const int n0 = ei[eidx];
    const int n1 = ei[N_EDGES + eidx];
    if (sq == 0) {
      float dx = coord[n0 * 3 + 0] - coord[n1 * 3 + 0];
      float dy = coord[n0 * 3 + 1] - coord[n1 * 3 + 1];
      float dz = coord[n0 * 3 + 2] - coord[n1 * 3 + 2];
      rows[se] = n0;
      rads[se] = dx * dx + dy * dy + dz * dz;
      msks[se] = edge_mask[eidx];
    }
#pragma unroll
    for (int pp = 0; pp < 2; ++pp) {
      const f32x4* src = (const f32x4*)(h + (pp ? n1 : n0) * D_F + sq * 32);
#pragma unroll
      for (int j = 0; j < 4; ++j) {
        f32x4 x0 = src[2 * j], x1 = src[2 * j + 1];
        FragU w;
        w.u[0] = cvt_pk_bf16(x0[0], x0[1]);
        w.u[1] = cvt_pk_bf16(x0[2], x0[3]);
        w.u[2] = cvt_pk_bf16(x1[0], x1[1]);
        w.u[3] = cvt_pk_bf16(x1[2], x1[3]);
        unsigned kb = (unsigned)(pp * 256 + sq * 64 + j * 16);
        *(s16x8*)(smem + F_OFF_A + (unsigned)(se * 512) + (kb ^ sswz)) = w.v;
      }
    }
    bar_lds();

    f32x4 acc[4][2];
#pragma unroll
    for (int mt = 0; mt < 4; ++mt)
#pragma unroll
      for (int nt = 0; nt < 2; ++nt) acc[mt][nt] = (f32x4){0.f, 0.f, 0.f, 0.f};
#pragma unroll
    for (int ks = 0; ks < 8; ++ks) {
      s16x8 a[4];
      unsigned kb = ((unsigned)((ks * 32 + lg * 8) * 2)) ^ rswz;
#pragma unroll
      for (int mt = 0; mt < 4; ++mt)
        a[mt] = *(const s16x8*)(smem + F_OFF_A + (unsigned)((mt * 16 + l15) * 512) + kb);
#pragma unroll
      for (int mt = 0; mt < 4; ++mt)
#pragma unroll
        for (int nt = 0; nt < 2; ++nt)
          acc[mt][nt] = __builtin_amdgcn_mfma_f32_16x16x32_bf16(a[mt], bw1[ks][nt].v,
                                                                acc[mt][nt], 0, 0, 0);
    }
#pragma unroll
    for (int mt = 0; mt < 4; ++mt)
#pragma unroll
      for (int nt = 0; nt < 2; ++nt)
#pragma unroll
        for (int q = 0; q < 4; ++q) {
          int e = mt * 16 + lg * 4 + q;
          float v = acc[mt][nt][q] + bv1[nt] + rads[e] * wlv[nt];
          v = silu_f(v);
          *(unsigned short*)(smem + F_OFF_M1 + (unsigned)(e * 256) +
                             ((unsigned)((c0 + nt * 16 + l15) * 2) ^
                              ((unsigned)((e & 7) << 4)))) =
              (unsigned short)cvt_pk_bf16(v, v);
        }
    bar_lds();

#pragma unroll
    for (int mt = 0; mt < 4; ++mt)
#pragma unroll
      for (int nt = 0; nt < 2; ++nt) acc[mt][nt] = (f32x4){0.f, 0.f, 0.f, 0.f};
#pragma unroll
    for (int ks = 0; ks < 4; ++ks) {
      s16x8 a[4];
      unsigned kb = ((unsigned)((ks * 32 + lg * 8) * 2)) ^ rswz;
#pragma unroll
      for (int mt = 0; mt < 4; ++mt)
        a[mt] = *(const s16x8*)(smem + F_OFF_M1 + (unsigned)((mt * 16 + l15) * 256) + kb);
#pragma unroll
      for (int mt = 0; mt < 4; ++mt)
#pragma unroll
        for (int nt = 0; nt < 2; ++nt)
          acc[mt][nt] = __builtin_amdgcn_mfma_f32_16x16x32_bf16(a[mt], bw2[ks][nt].v,
                                                                acc[mt][nt], 0, 0, 0);
    }
    if (SORTED) {
#pragma unroll
      for (int mt = 0; mt < 4; ++mt)
#pragma unroll
        for (int nt = 0; nt < 2; ++nt)
#pragma unroll
          for (int q = 0; q < 4; ++q) {
            int e = mt * 16 + lg * 4 + q;
            float v = silu_f(acc[mt][nt][q] + bv2[nt]) * msks[e];
            int col = c0 + nt * 16 + l15;
            *(unsigned short*)(smem + F_OFF_M2 + (unsigned)(e * 256) +
                               ((unsigned)(col * 2) ^ ((unsigned)((e & 7) << 4)))) =
                (unsigned short)cvt_pk_bf16(v, v);
          }
      bar_lds();
      {
        const int colw = tid & 127, half = tid >> 7;
        float a = 0.f;
        int cur = rows[half * 32];
#pragma unroll 8
        for (int i = 0; i < 32; ++i) {
          int e = half * 32 + i;
          float v = bf2f(*(const unsigned short*)(
              smem + F_OFF_M2 + (unsigned)(e * 256) +
              ((unsigned)(colw * 2) ^ ((unsigned)((e & 7) << 4)))));
          int r = rows[e];
          if (r != cur) { atomicAdd(agg + (size_t)cur * D_F + colw, a); a = 0.f; cur = r; }
          a += v;
        }
        atomicAdd(agg + (size_t)cur * D_F + colw, a);
      }
    } else {
#pragma unroll
      for (int mt = 0; mt < 4; ++mt)
#pragma unroll
        for (int q = 0; q < 4; ++q) {
          int e = mt * 16 + lg * 4 + q;
          int r = rows[e];
          float mk = msks[e];
#pragma unroll
          for (int nt = 0; nt < 2; ++nt) {
            float v = silu_f(acc[mt][nt][q] + bv2[nt]) * mk;
            atomicAdd(agg + (size_t)r * D_F + c0 + nt * 16 + l15, v);
          }
        }
    }
    bar_lds();
  }
}

// ================= node kernel (MFMA, residual) =================
#define NOFF_A  0u
#define NOFF_M1 32768u
#define NODE_LDS 49152u

__global__ __launch_bounds__(256)
void egcl_node_kernel(const float* __restrict__ h, const float* __restrict__ agg,
                      const float* __restrict__ Wn1, const float* __restrict__ bn1,
                      const float* __restrict__ Wn2, const float* __restrict__ bn2,
                      float* __restrict__ out) {
  extern __shared__ __attribute__((aligned(16))) char smem[];
  const int tid  = threadIdx.x;
  const int lane = tid & 63;
  const int wv   = tid >> 6;
  const int l15  = lane & 15;
  const int lg   = lane >> 4;
  const int c0   = wv * 32;
  const int col0 = c0 + l15;
  const int base = blockIdx.x * 64;

  FragU bw1[8][2];
  FragU bw2[4][2];
#pragma unroll
  for (int kt = 0; kt < 8; ++kt)
#pragma unroll
    for (int nt = 0; nt < 2; ++nt) {
      const int col = col0 + nt * 16;
      const int kb = kt * 32 + lg * 8;
#pragma unroll
      for (int j = 0; j < 4; ++j)
        bw1[kt][nt].u[j] = cvt_pk_bf16(Wn1[(kb + 2 * j) * D_F + col],
                                       Wn1[(kb + 2 * j + 1) * D_F + col]);
    }
#pragma unroll
  for (int kt = 0; kt < 4; ++kt)
#pragma unroll
    for (int nt = 0; nt < 2; ++nt) {
      const int col = col0 + nt * 16;
      const int kb = kt * 32 + lg * 8;
#pragma unroll
      for (int j = 0; j < 4; ++j)
        bw2[kt][nt].u[j] = cvt_pk_bf16(Wn2[(kb + 2 * j) * D_F + col],
                                       Wn2[(kb + 2 * j + 1) * D_F + col]);
    }
  const float bv1[2] = {bn1[col0], bn1[col0 + 16]};
  const float bv2[2] = {bn2[col0], bn2[col0 + 16]};

  const int se = tid >> 2;
  const int sq = tid & 3;
  const unsigned sswz = (unsigned)((se & 7) << 4);
  const unsigned rswz = (unsigned)((l15 & 7) << 4);
  const int node = base + se;

#pragma unroll
  for (int p = 0; p < 2; ++p) {
    FragU w;
    if (node < N_NODES) {
      const f32x4* src = (const f32x4*)((p ? agg : h) + node * D_F + sq * 32);
#pragma unroll
      for (int j = 0; j < 4; ++j) {
        f32x4 x0 = src[2 * j], x1 = src[2 * j + 1];
        w.u[0] = cvt_pk_bf16(x0[0], x0[1]);
        w.u[1] = cvt_pk_bf16(x0[2], x0[3]);
        w.u[2] = cvt_pk_bf16(x1[0], x1[1]);
        w.u[3] = cvt_pk_bf16(x1[2], x1[3]);
        unsigned kb = (unsigned)(p * 256 + sq * 64 + j * 16);
        *(s16x8*)(smem + NOFF_A + (unsigned)(se * 512) + (kb ^ sswz)) = w.v;
      }
    } else {
      w.u[0] = w.u[1] = w.u[2] = w.u[3] = 0u;
#pragma unroll
      for (int j = 0; j < 4; ++j) {
        unsigned kb = (unsigned)(p * 256 + sq * 64 + j * 16);
        *(s16x8*)(smem + NOFF_A + (unsigned)(se * 512) + (kb ^ sswz)) = w.v;
      }
    }
  }
  bar_lds();

  f32x4 acc[4][2];
#pragma unroll
  for (int mt = 0; mt < 4; ++mt)
#pragma unroll
    for (int nt = 0; nt < 2; ++nt) acc[mt][nt] = (f32x4){0.f, 0.f, 0.f, 0.f};
#pragma unroll
  for (int ks = 0; ks < 8; ++ks) {
    s16x8 a[4];
    unsigned kb = ((unsigned)((ks * 32 + lg * 8) * 2)) ^ rswz;
#pragma unroll
    for (int mt = 0; mt < 4; ++mt)
      a[mt] = *(const s16x8*)(smem + NOFF_A + (unsigned)((mt * 16 + l15) * 512) + kb);
#pragma unroll
    for (int mt = 0; mt < 4; ++mt)
#pragma unroll
      for (int nt = 0; nt < 2; ++nt)
        acc[mt][nt] = __builtin_amdgcn_mfma_f32_16x16x32_bf16(a[mt], bw1[ks][nt].v,
                                                              acc[mt][nt], 0, 0, 0);
  }
#pragma unroll
  for (int mt = 0; mt < 4; ++mt)
#pragma unroll
    for (int nt = 0; nt < 2; ++nt)
#pragma unroll
      for (int q = 0; q < 4; ++q) {
        int e = mt * 16 + lg * 4 + q;
        float v = silu_f(acc[mt][nt][q] + bv1[nt]);
        *(unsigned short*)(smem + NOFF_M1 + (unsigned)(e * 256) +
                           ((unsigned)((c0 + nt * 16 + l15) * 2) ^
                            ((unsigned)((e & 7) << 4)))) =
            (unsigned short)cvt_pk_bf16(v, v);
      }
  bar_lds();

#pragma unroll
  for (int mt = 0; mt < 4; ++mt)
#pragma unroll
    for (int nt = 0; nt < 2; ++nt) acc[mt][nt] = (f32x4){0.f, 0.f, 0.f, 0.f};
#pragma unroll
  for (int ks = 0; ks < 4; ++ks) {
    s16x8 a[4];
    unsigned kb = ((unsigned)((ks * 32 + lg * 8) * 2)) ^ rswz;
#pragma unroll
    for (int mt = 0; mt < 4; ++mt)
      a[mt] = *(const s16x8*)(smem + NOFF_M1 + (unsigned)((mt * 16 + l15) * 256) + kb);
#pragma unroll
    for (int mt = 0; mt < 4; ++mt)
#pragma unroll
      for (int nt = 0; nt < 2; ++nt)
        acc[mt][nt] = __builtin_amdgcn_mfma_f32_16x16x32_bf16(a[mt], bw2[ks][nt].v,
                                                              acc[mt][nt], 0, 0, 0);
  }
#pragma unroll
  for (int mt = 0; mt < 4; ++mt)
#pragma unroll
    for (int q = 0; q < 4; ++q) {
      int nd = base + mt * 16 + lg * 4 + q;
      if (nd < N_NODES) {
#pragma unroll
        for (int nt = 0; nt < 2; ++nt) {
          int col = c0 + nt * 16 + l15;
          out[nd * D_F + col] = h[nd * D_F + col] + acc[mt][nt][q] + bv2[nt];
        }
      }
    }
}

extern "C" void kernel_launch(void* const* d_in, const int* in_sizes, int n_in,
                              void* d_out, int out_size, void* d_ws, size_t ws_size,
                              hipStream_t stream) {
  (void)in_sizes; (void)n_in; (void)out_size;
  const float* h         = (const float*)d_in[0];
  const float* coord     = (const float*)d_in[1];
  const float* edge_mask = (const float*)d_in[2];
  const float* We1       = (const float*)d_in[3];
  const float* be1       = (const float*)d_in[4];
  const float* We2       = (const float*)d_in[5];
  const float* be2       = (const float*)d_in[6];
  const float* Wn1       = (const float*)d_in[7];
  const float* bn1       = (const float*)d_in[8];
  const float* Wn2       = (const float*)d_in[9];
  const float* bn2       = (const float*)d_in[10];
  const int*   ei        = (const int*)d_in[11];
  float* out = (float*)d_out;
  char* ws = (char*)d_ws;
  float* agg = (float*)(ws + WS_AGG);

  hipFuncSetAttribute((const void*)egcl_edge2,
                      hipFuncAttributeMaxDynamicSharedMemorySize, (int)E2_LDS);
  hipFuncSetAttribute((const void*)egcl_node_kernel,
                      hipFuncAttributeMaxDynamicSharedMemorySize, (int)NODE_LDS);

  if (ws_size >= (size_t)WS_FULL_NEED) {
    unsigned* rcarr  = (unsigned*)(ws + WS_RC);
    float2*   radm   = (float2*)(ws + WS_RADM);
    int*      counts = (int*)(ws + WS_COUNTS);
    int*      cursor = (int*)(ws + WS_CURSOR);
    unsigned short* hbf = (unsigned short*)d_out;  // scratch; node kernel overwrites later

    prep_kernel<<<(N_NODES * D_F / 4 + 255) / 256, 256, 0, stream>>>(h, hbf, agg, counts);
    hist_kernel<<<512, 256, 0, stream>>>(ei, counts);
    scan_kernel<<<1, 1024, 0, stream>>>(counts, cursor);
    scatter2_kernel<<<512, 256, 0, stream>>>(ei, coord, edge_mask, cursor, rcarr, radm);
    egcl_edge2<<<GRID2, 256, E2_LDS, stream>>>(
        hbf, We1, be1, We2, be2, rcarr, radm, agg);
  } else if (ws_size >= (size_t)F_WS_NEED) {
    int* counts = (int*)(ws + F_WS_COUNTS);
    int* cursor = (int*)(ws + F_WS_CURSOR);
    int* perm   = (int*)(ws + F_WS_PERM);
    hipFuncSetAttribute((const void*)egcl_edge_fb<true>,
                        hipFuncAttributeMaxDynamicSharedMemorySize, (int)F_EDGE_LDS);
    hipMemsetAsync(ws, 0, F_WS_CURSOR, stream);
    hist_kernel<<<512, 256, 0, stream>>>(ei, counts);
    scan_kernel<<<1, 1024, 0, stream>>>(counts, cursor);
    scatter_kernel<<<512, 256, 0, stream>>>(ei, cursor, perm);
    egcl_edge_fb<true><<<768, 256, F_EDGE_LDS, stream>>>(
        h, coord, edge_mask, We1, be1, We2, be2, ei, perm, agg);
  } else {
    hipFuncSetAttribute((const void*)egcl_edge_fb<false>,
                        hipFuncAttributeMaxDynamicSharedMemorySize, (int)F_EDGE_LDS);
    hipMemsetAsync(agg, 0, (size_t)N_NODES * D_F * sizeof(float), stream);
    egcl_edge_fb<false><<<768, 256, F_EDGE_LDS, stream>>>(
        h, coord, edge_mask, We1, be1, We2, be2, ei, nullptr, agg);
  }
  egcl_node_kernel<<<(N_NODES + 63) / 64, 256, NODE_LDS, stream>>>(
      h, agg, Wn1, bn1, Wn2, bn2, out);
}